// Round 1
// baseline (1095.944 us; speedup 1.0000x reference)
//
#include <hip/hip_runtime.h>
#include <cmath>

#define B_    16
#define S_    1024
#define D_    256
#define H_    8
#define DH_   32
#define DFF_  1024
#define PDIM_ 64
#define N_    (B_ * S_)      // 16384
#define E_    262144
#define ETOT_ (E_ + N_)      // 278528
#define EPS_  1e-5f

// ---------------- wave helpers ----------------
__device__ __forceinline__ float wave_sum(float v) {
#pragma unroll
  for (int m = 1; m < 64; m <<= 1) v += __shfl_xor(v, m, 64);
  return v;
}
__device__ __forceinline__ float wave_max(float v) {
#pragma unroll
  for (int m = 1; m < 64; m <<= 1) v = fmaxf(v, __shfl_xor(v, m, 64));
  return v;
}

// ---------------- gamma/beta for both AdaLNs ----------------
// gamma[b][d] = prop_cond[b,:] . gw[d,:] + gb[d]
__global__ __launch_bounds__(256) void gamma_beta_kernel(
    const float* __restrict__ pc,
    const float* __restrict__ g1w, const float* __restrict__ g1b,
    const float* __restrict__ b1w, const float* __restrict__ b1b,
    const float* __restrict__ g2w, const float* __restrict__ g2b,
    const float* __restrict__ b2w, const float* __restrict__ b2b,
    float* __restrict__ gamma1, float* __restrict__ beta1,
    float* __restrict__ gamma2, float* __restrict__ beta2) {
  int i = blockIdx.x * 256 + threadIdx.x;
  if (i >= B_ * D_) return;
  int b = i >> 8, d = i & 255;
  const float* p = pc + b * PDIM_;
  float s1 = 0.f, s2 = 0.f, s3 = 0.f, s4 = 0.f;
#pragma unroll 8
  for (int k = 0; k < PDIM_; ++k) {
    float pv = p[k];
    s1 += pv * g1w[d * PDIM_ + k];
    s2 += pv * b1w[d * PDIM_ + k];
    s3 += pv * g2w[d * PDIM_ + k];
    s4 += pv * b2w[d * PDIM_ + k];
  }
  gamma1[i] = s1 + g1b[d];
  beta1[i]  = s2 + b1b[d];
  gamma2[i] = s3 + g2b[d];
  beta2[i]  = s4 + b2b[d];
}

// ---------------- AdaLN (plain LN -> gamma*xhat+beta -> LN(w,b)) ----------------
// one wave per row; lane holds 4 contiguous elements (D=256 = 64 lanes * 4)
__global__ __launch_bounds__(256) void adaln_kernel(
    const float* __restrict__ x, const float* __restrict__ gamma,
    const float* __restrict__ beta, const float* __restrict__ lnw,
    const float* __restrict__ lnb, float* __restrict__ out) {
  int wid = threadIdx.x >> 6, lane = threadIdx.x & 63;
  int r = blockIdx.x * 4 + wid;  // row in [0,N)
  int b = r >> 10;               // batch
  const int c = lane << 2;
  float4 v = *(const float4*)&x[(size_t)r * D_ + c];
  float sum = wave_sum(v.x + v.y + v.z + v.w);
  float mu = sum * (1.f / D_);
  float d0 = v.x - mu, d1 = v.y - mu, d2 = v.z - mu, d3 = v.w - mu;
  float sq = wave_sum(d0 * d0 + d1 * d1 + d2 * d2 + d3 * d3);
  float rs = rsqrtf(sq * (1.f / D_) + EPS_);
  float4 g  = *(const float4*)&gamma[b * D_ + c];
  float4 be = *(const float4*)&beta[b * D_ + c];
  float a0 = g.x * (d0 * rs) + be.x;
  float a1 = g.y * (d1 * rs) + be.y;
  float a2 = g.z * (d2 * rs) + be.z;
  float a3 = g.w * (d3 * rs) + be.w;
  float sum2 = wave_sum(a0 + a1 + a2 + a3);
  float mu2 = sum2 * (1.f / D_);
  float e0 = a0 - mu2, e1 = a1 - mu2, e2 = a2 - mu2, e3 = a3 - mu2;
  float sq2 = wave_sum(e0 * e0 + e1 * e1 + e2 * e2 + e3 * e3);
  float rs2 = rsqrtf(sq2 * (1.f / D_) + EPS_);
  float4 w  = *(const float4*)&lnw[c];
  float4 bb = *(const float4*)&lnb[c];
  float4 o;
  o.x = e0 * rs2 * w.x + bb.x;
  o.y = e1 * rs2 * w.y + bb.y;
  o.z = e2 * rs2 * w.z + bb.z;
  o.w = e3 * rs2 * w.w + bb.w;
  *(float4*)&out[(size_t)r * D_ + c] = o;
}

// ---------------- fp32 tiled GEMM: C[M,Nc] = A[M,K] @ W[Nc,K]^T (+bias)(+epi) ----------------
// EPI: 0 = none, 1 = exact GELU, 2 = add residual R
template <int EPI>
__global__ __launch_bounds__(256) void gemm_bt_kernel(
    const float* __restrict__ A, const float* __restrict__ Wt,
    const float* __restrict__ bias, const float* __restrict__ R,
    float* __restrict__ C, int M, int Nc, int K) {
  __shared__ __align__(16) float As[16][68];
  __shared__ __align__(16) float Bs[16][68];
  const int bm = blockIdx.y * 64;
  const int bn = blockIdx.x * 64;
  const int t = threadIdx.x;
  const int tx = t & 15, ty = t >> 4;
  const int lr = t >> 2;
  const int lk = (t & 3) << 2;
  float acc[4][4] = {};
  const float* Aload = A + (size_t)(bm + lr) * K + lk;
  const float* Wload = Wt + (size_t)(bn + lr) * K + lk;
  for (int k0 = 0; k0 < K; k0 += 16) {
    __syncthreads();
    float4 av = *(const float4*)(Aload + k0);
    float4 wv = *(const float4*)(Wload + k0);
    As[lk + 0][lr] = av.x; As[lk + 1][lr] = av.y;
    As[lk + 2][lr] = av.z; As[lk + 3][lr] = av.w;
    Bs[lk + 0][lr] = wv.x; Bs[lk + 1][lr] = wv.y;
    Bs[lk + 2][lr] = wv.z; Bs[lk + 3][lr] = wv.w;
    __syncthreads();
#pragma unroll
    for (int kk = 0; kk < 16; ++kk) {
      const float4 a = *(const float4*)&As[kk][ty << 2];
      const float4 b = *(const float4*)&Bs[kk][tx << 2];
      acc[0][0] += a.x * b.x; acc[0][1] += a.x * b.y; acc[0][2] += a.x * b.z; acc[0][3] += a.x * b.w;
      acc[1][0] += a.y * b.x; acc[1][1] += a.y * b.y; acc[1][2] += a.y * b.z; acc[1][3] += a.y * b.w;
      acc[2][0] += a.z * b.x; acc[2][1] += a.z * b.y; acc[2][2] += a.z * b.z; acc[2][3] += a.z * b.w;
      acc[3][0] += a.w * b.x; acc[3][1] += a.w * b.y; acc[3][2] += a.w * b.z; acc[3][3] += a.w * b.w;
    }
  }
#pragma unroll
  for (int i = 0; i < 4; ++i) {
    int row = bm + (ty << 2) + i;
    size_t base = (size_t)row * Nc + bn + (tx << 2);
#pragma unroll
    for (int j = 0; j < 4; ++j) {
      float v = acc[i][j];
      if (bias) v += bias[bn + (tx << 2) + j];
      if (EPI == 1) v = 0.5f * v * (1.f + erff(v * 0.7071067811865476f));
      if (EPI == 2) v += R[base + j];
      C[base + j] = v;
    }
  }
}

// ---------------- flash attention, one thread per query ----------------
// qkv layout: [N, 768]; q at col h*32, k at 256+h*32, v at 512+h*32
__global__ __launch_bounds__(128) void attn_kernel(
    const float* __restrict__ qkv, float* __restrict__ ao) {
  const int qt = blockIdx.x;   // 0..7 (128-query tile)
  const int h = blockIdx.y;    // 0..7
  const int b = blockIdx.z;    // 0..15
  const int t = threadIdx.x;   // 0..127
  const int q = qt * 128 + t;
  const float scale = 0.17677669529663687f;  // 1/sqrt(32)

  float qreg[32];
  {
    const size_t rowq = ((size_t)b * S_ + q) * 768 + h * DH_;
#pragma unroll
    for (int i = 0; i < 8; ++i) {
      float4 v = *(const float4*)&qkv[rowq + i * 4];
      qreg[i * 4 + 0] = v.x; qreg[i * 4 + 1] = v.y;
      qreg[i * 4 + 2] = v.z; qreg[i * 4 + 3] = v.w;
    }
  }
  __shared__ __align__(16) float Ks[64][32];
  __shared__ __align__(16) float Vs[64][32];
  float acc[32] = {};
  float m = -1e30f, l = 0.f;

  for (int kt = 0; kt < 16; ++kt) {
    __syncthreads();
#pragma unroll
    for (int i = 0; i < 4; ++i) {
      int idx = t + i * 128;       // 0..511
      int key = idx >> 3, f4 = (idx & 7) << 2;
      size_t rk = ((size_t)b * S_ + kt * 64 + key) * 768 + 256 + h * DH_ + f4;
      *(float4*)&Ks[key][f4] = *(const float4*)&qkv[rk];
      *(float4*)&Vs[key][f4] = *(const float4*)&qkv[rk + 256];
    }
    __syncthreads();
    for (int key = 0; key < 64; ++key) {
      float s = 0.f;
#pragma unroll
      for (int d = 0; d < 32; ++d) s += qreg[d] * Ks[key][d];
      s *= scale;
      if (s <= m) {
        float p = __expf(s - m);
        l += p;
#pragma unroll
        for (int d = 0; d < 32; ++d) acc[d] += p * Vs[key][d];
      } else {
        float r = __expf(m - s);
        l = l * r + 1.f;
#pragma unroll
        for (int d = 0; d < 32; ++d) acc[d] = acc[d] * r + Vs[key][d];
        m = s;
      }
    }
  }
  float inv = 1.f / l;
  const size_t rowo = ((size_t)b * S_ + q) * D_ + h * DH_;
#pragma unroll
  for (int i = 0; i < 8; ++i) {
    float4 o;
    o.x = acc[i * 4 + 0] * inv; o.y = acc[i * 4 + 1] * inv;
    o.z = acc[i * 4 + 2] * inv; o.w = acc[i * 4 + 3] * inv;
    *(float4*)&ao[rowo + i * 4] = o;
  }
}

// ---------------- a_src/a_dst: per-node dots ----------------
__global__ __launch_bounds__(256) void adot_kernel(
    const float* __restrict__ h, const float* __restrict__ att_src,
    const float* __restrict__ att_dst, float* __restrict__ a_src,
    float* __restrict__ a_dst) {
  int wid = threadIdx.x >> 6, lane = threadIdx.x & 63;
  int n = blockIdx.x * 4 + wid;
  const int c = lane << 2;
  float4 hv = *(const float4*)&h[(size_t)n * D_ + c];
  float4 as = *(const float4*)&att_src[c];
  float4 ad = *(const float4*)&att_dst[c];
  float s = hv.x * as.x + hv.y * as.y + hv.z * as.z + hv.w * as.w;
  float d = hv.x * ad.x + hv.y * ad.y + hv.z * ad.z + hv.w * ad.w;
  s = wave_sum(s);
  d = wave_sum(d);
  if (lane == 0) { a_src[n] = s; a_dst[n] = d; }
}

// ---------------- GAT CSR build ----------------
__global__ __launch_bounds__(256) void hist_kernel(
    const int* __restrict__ e_dst, int* __restrict__ counts) {
  int i = blockIdx.x * 256 + threadIdx.x;
  if (i >= ETOT_) return;
  int dst = (i < E_) ? e_dst[i] : (i - E_);
  atomicAdd(&counts[dst], 1);
}

__global__ __launch_bounds__(1024) void scan_kernel(
    const int* __restrict__ counts, int* __restrict__ offsets,
    int* __restrict__ cursor) {
  __shared__ int sums[1024];
  const int t = threadIdx.x;
  int local[16];
  int s = 0;
#pragma unroll
  for (int i = 0; i < 16; ++i) { local[i] = s; s += counts[t * 16 + i]; }
  sums[t] = s;
  __syncthreads();
  for (int off = 1; off < 1024; off <<= 1) {
    int v = (t >= off) ? sums[t - off] : 0;
    __syncthreads();
    sums[t] += v;
    __syncthreads();
  }
  int base = (t > 0) ? sums[t - 1] : 0;
#pragma unroll
  for (int i = 0; i < 16; ++i) {
    int o = base + local[i];
    offsets[t * 16 + i] = o;
    cursor[t * 16 + i] = o;
  }
  if (t == 1023) offsets[N_] = sums[1023];
}

__global__ __launch_bounds__(256) void scatter_kernel(
    const int* __restrict__ e_src, const int* __restrict__ e_dst,
    int* __restrict__ cursor, int* __restrict__ csr_src) {
  int i = blockIdx.x * 256 + threadIdx.x;
  if (i >= ETOT_) return;
  int s = (i < E_) ? e_src[i] : (i - E_);
  int d = (i < E_) ? e_dst[i] : (i - E_);
  int slot = atomicAdd(&cursor[d], 1);
  csr_src[slot] = s;
}

// ---------------- GAT aggregate + bias + residual + gLN (one wave per node) ----------------
__global__ __launch_bounds__(256) void gat_ln_kernel(
    const float* __restrict__ h, const float* __restrict__ a_src,
    const float* __restrict__ a_dst, const int* __restrict__ offsets,
    const int* __restrict__ csr_src, const float* __restrict__ gat_bias,
    const float* __restrict__ x1, const float* __restrict__ gln_w,
    const float* __restrict__ gln_b, float* __restrict__ x2) {
  int wid = threadIdx.x >> 6, lane = threadIdx.x & 63;
  int n = blockIdx.x * 4 + wid;
  const int c = lane << 2;
  int beg = offsets[n], end = offsets[n + 1];
  float adn = a_dst[n];
  // pass 1: segment max
  float m = -1e30f;
  for (int j = beg + lane; j < end; j += 64) {
    float e = a_src[csr_src[j]] + adn;
    e = (e >= 0.f) ? e : 0.2f * e;
    m = fmaxf(m, e);
  }
  m = wave_max(m);
  // pass 2: weights + aggregation
  float z = 0.f;
  float ac0 = 0.f, ac1 = 0.f, ac2 = 0.f, ac3 = 0.f;
  for (int j0 = beg; j0 < end; j0 += 64) {
    int j = j0 + lane;
    float w = 0.f;
    int sidx = 0;
    if (j < end) {
      sidx = csr_src[j];
      float e = a_src[sidx] + adn;
      e = (e >= 0.f) ? e : 0.2f * e;
      w = __expf(e - m);
    }
    z += w;
    int cnt = min(64, end - j0);
    for (int jj = 0; jj < cnt; ++jj) {
      float ww = __shfl(w, jj, 64);
      int ss = __shfl(sidx, jj, 64);
      float4 hv = *(const float4*)&h[(size_t)ss * D_ + c];
      ac0 += ww * hv.x; ac1 += ww * hv.y; ac2 += ww * hv.z; ac3 += ww * hv.w;
    }
  }
  z = wave_sum(z);
  float inv = 1.f / z;
  float4 bv = *(const float4*)&gat_bias[c];
  float4 xv = *(const float4*)&x1[(size_t)n * D_ + c];
  float v0 = ac0 * inv + bv.x + xv.x;
  float v1 = ac1 * inv + bv.y + xv.y;
  float v2 = ac2 * inv + bv.z + xv.z;
  float v3 = ac3 * inv + bv.w + xv.w;
  // gLN
  float sum = wave_sum(v0 + v1 + v2 + v3);
  float mu = sum * (1.f / D_);
  float d0 = v0 - mu, d1 = v1 - mu, d2 = v2 - mu, d3 = v3 - mu;
  float sq = wave_sum(d0 * d0 + d1 * d1 + d2 * d2 + d3 * d3);
  float rs = rsqrtf(sq * (1.f / D_) + EPS_);
  float4 w4 = *(const float4*)&gln_w[c];
  float4 b4 = *(const float4*)&gln_b[c];
  float4 o;
  o.x = d0 * rs * w4.x + b4.x;
  o.y = d1 * rs * w4.y + b4.y;
  o.z = d2 * rs * w4.z + b4.z;
  o.w = d3 * rs * w4.w + b4.w;
  *(float4*)&x2[(size_t)n * D_ + c] = o;
}

// ---------------- launch ----------------
extern "C" void kernel_launch(void* const* d_in, const int* in_sizes, int n_in,
                              void* d_out, int out_size, void* d_ws,
                              size_t ws_size, hipStream_t stream) {
  const float* x         = (const float*)d_in[0];
  const float* prop_cond = (const float*)d_in[1];
  const int*   edges     = (const int*)d_in[2];
  const float* a1gw = (const float*)d_in[3];
  const float* a1gb = (const float*)d_in[4];
  const float* a1bw = (const float*)d_in[5];
  const float* a1bb = (const float*)d_in[6];
  const float* a2gw = (const float*)d_in[7];
  const float* a2gb = (const float*)d_in[8];
  const float* a2bw = (const float*)d_in[9];
  const float* a2bb = (const float*)d_in[10];
  const float* ln1w = (const float*)d_in[11];
  const float* ln1b = (const float*)d_in[12];
  const float* ln2w = (const float*)d_in[13];
  const float* ln2b = (const float*)d_in[14];
  const float* glnw = (const float*)d_in[15];
  const float* glnb = (const float*)d_in[16];
  const float* ipw  = (const float*)d_in[17];
  const float* ipb  = (const float*)d_in[18];
  const float* opw  = (const float*)d_in[19];
  const float* opb  = (const float*)d_in[20];
  const float* f1w  = (const float*)d_in[21];
  const float* f1b  = (const float*)d_in[22];
  const float* f2w  = (const float*)d_in[23];
  const float* f2b  = (const float*)d_in[24];
  const float* gatw = (const float*)d_in[25];
  const float* gats = (const float*)d_in[26];
  const float* gatd = (const float*)d_in[27];
  const float* gatb = (const float*)d_in[28];
  float* out = (float*)d_out;

  const int* e_src = edges;
  const int* e_dst = edges + E_;

  // workspace layout (floats)
  float* W = (float*)d_ws;
  const size_t F_BIG = 0;                             // 16M floats: qkv then ff1
  const size_t F_XN  = F_BIG + 16777216;              // 4M: xn1 -> ao -> xn2
  const size_t F_X1  = F_XN + 4194304;                // 4M: x after attention
  const size_t F_H   = F_X1 + 4194304;                // 4M: GAT h
  const size_t F_X2  = F_H + 4194304;                 // 4M: post-GAT/gLN x
  const size_t F_GB  = F_X2 + 4194304;                // 16K: gammas/betas
  const size_t F_AS  = F_GB + 16384;                  // a_src
  const size_t F_AD  = F_AS + N_;                     // a_dst
  const size_t F_INT = F_AD + N_;
  float* buf_big = W + F_BIG;
  float* buf_xn  = W + F_XN;
  float* buf_x1  = W + F_X1;
  float* buf_h   = W + F_H;
  float* buf_x2  = W + F_X2;
  float* gamma1  = W + F_GB;
  float* beta1   = gamma1 + 4096;
  float* gamma2  = beta1 + 4096;
  float* beta2   = gamma2 + 4096;
  float* a_src   = W + F_AS;
  float* a_dst   = W + F_AD;
  int* counts  = (int*)(W + F_INT);
  int* offsets = counts + N_;        // N_+1 entries
  int* cursor  = offsets + N_ + 1;
  int* csr_src = cursor + N_;

  // zero the histogram (ws is poisoned before every call)
  hipMemsetAsync(counts, 0, N_ * sizeof(int), stream);

  // gamma/beta for both AdaLNs
  gamma_beta_kernel<<<16, 256, 0, stream>>>(prop_cond, a1gw, a1gb, a1bw, a1bb,
                                            a2gw, a2gb, a2bw, a2bb, gamma1,
                                            beta1, gamma2, beta2);
  // AdaLN1 + LN1 -> xn1
  adaln_kernel<<<N_ / 4, 256, 0, stream>>>(x, gamma1, beta1, ln1w, ln1b, buf_xn);
  // QKV projection
  gemm_bt_kernel<0><<<dim3(12, 256), 256, 0, stream>>>(buf_xn, ipw, ipb, nullptr,
                                                       buf_big, N_, 768, 256);
  // attention -> ao (reuse xn buffer)
  attn_kernel<<<dim3(8, 8, 16), 128, 0, stream>>>(buf_big, buf_xn);
  // out_proj + residual(x) -> x1
  gemm_bt_kernel<2><<<dim3(4, 256), 256, 0, stream>>>(buf_xn, opw, opb, x,
                                                      buf_x1, N_, 256, 256);
  // GAT: h = x1 @ gat_w^T
  gemm_bt_kernel<0><<<dim3(4, 256), 256, 0, stream>>>(buf_x1, gatw, nullptr,
                                                      nullptr, buf_h, N_, 256, 256);
  adot_kernel<<<N_ / 4, 256, 0, stream>>>(buf_h, gats, gatd, a_src, a_dst);
  hist_kernel<<<(ETOT_ + 255) / 256, 256, 0, stream>>>(e_dst, counts);
  scan_kernel<<<1, 1024, 0, stream>>>(counts, offsets, cursor);
  scatter_kernel<<<(ETOT_ + 255) / 256, 256, 0, stream>>>(e_src, e_dst, cursor,
                                                          csr_src);
  gat_ln_kernel<<<N_ / 4, 256, 0, stream>>>(buf_h, a_src, a_dst, offsets,
                                            csr_src, gatb, buf_x1, glnw, glnb,
                                            buf_x2);
  // AdaLN2 + LN2 -> xn2 (reuse xn buffer)
  adaln_kernel<<<N_ / 4, 256, 0, stream>>>(buf_x2, gamma2, beta2, ln2w, ln2b,
                                           buf_xn);
  // FFN1 + GELU -> big buffer (qkv dead)
  gemm_bt_kernel<1><<<dim3(16, 256), 256, 0, stream>>>(buf_xn, f1w, f1b, nullptr,
                                                       buf_big, N_, DFF_, 256);
  // FFN2 + residual(x2) -> out
  gemm_bt_kernel<2><<<dim3(4, 256), 256, 0, stream>>>(buf_big, f2w, f2b, buf_x2,
                                                      out, N_, 256, DFF_);
}

// Round 2
// 788.639 us; speedup vs baseline: 1.3897x; 1.3897x over previous
//
#include <hip/hip_runtime.h>
#include <cmath>

#define B_    16
#define S_    1024
#define D_    256
#define H_    8
#define DH_   32
#define DFF_  1024
#define PDIM_ 64
#define N_    (B_ * S_)      // 16384
#define E_    262144
#define ETOT_ (E_ + N_)      // 278528
#define EPS_  1e-5f

typedef __attribute__((ext_vector_type(8))) short bf16x8;
typedef __attribute__((ext_vector_type(4))) float f32x4;

// ---------------- wave helpers ----------------
__device__ __forceinline__ float wave_sum(float v) {
#pragma unroll
  for (int m = 1; m < 64; m <<= 1) v += __shfl_xor(v, m, 64);
  return v;
}
__device__ __forceinline__ float wave_max(float v) {
#pragma unroll
  for (int m = 1; m < 64; m <<= 1) v = fmaxf(v, __shfl_xor(v, m, 64));
  return v;
}

// bf16 split helpers (RNE)
__device__ __forceinline__ unsigned short f2bf(float f) {
  unsigned int u = __float_as_uint(f);
  unsigned int r = u + 0x7fffu + ((u >> 16) & 1u);
  return (unsigned short)(r >> 16);
}
__device__ __forceinline__ float bf2f(unsigned short s) {
  return __uint_as_float(((unsigned int)s) << 16);
}

// ---------------- gamma/beta for both AdaLNs ----------------
__global__ __launch_bounds__(256) void gamma_beta_kernel(
    const float* __restrict__ pc,
    const float* __restrict__ g1w, const float* __restrict__ g1b,
    const float* __restrict__ b1w, const float* __restrict__ b1b,
    const float* __restrict__ g2w, const float* __restrict__ g2b,
    const float* __restrict__ b2w, const float* __restrict__ b2b,
    float* __restrict__ gamma1, float* __restrict__ beta1,
    float* __restrict__ gamma2, float* __restrict__ beta2) {
  int i = blockIdx.x * 256 + threadIdx.x;
  if (i >= B_ * D_) return;
  int b = i >> 8, d = i & 255;
  const float* p = pc + b * PDIM_;
  float s1 = 0.f, s2 = 0.f, s3 = 0.f, s4 = 0.f;
#pragma unroll 8
  for (int k = 0; k < PDIM_; ++k) {
    float pv = p[k];
    s1 += pv * g1w[d * PDIM_ + k];
    s2 += pv * b1w[d * PDIM_ + k];
    s3 += pv * g2w[d * PDIM_ + k];
    s4 += pv * b2w[d * PDIM_ + k];
  }
  gamma1[i] = s1 + g1b[d];
  beta1[i]  = s2 + b1b[d];
  gamma2[i] = s3 + g2b[d];
  beta2[i]  = s4 + b2b[d];
}

// ---------------- AdaLN (plain LN -> gamma*xhat+beta -> LN(w,b)) ----------------
__global__ __launch_bounds__(256) void adaln_kernel(
    const float* __restrict__ x, const float* __restrict__ gamma,
    const float* __restrict__ beta, const float* __restrict__ lnw,
    const float* __restrict__ lnb, float* __restrict__ out) {
  int wid = threadIdx.x >> 6, lane = threadIdx.x & 63;
  int r = blockIdx.x * 4 + wid;
  int b = r >> 10;
  const int c = lane << 2;
  float4 v = *(const float4*)&x[(size_t)r * D_ + c];
  float sum = wave_sum(v.x + v.y + v.z + v.w);
  float mu = sum * (1.f / D_);
  float d0 = v.x - mu, d1 = v.y - mu, d2 = v.z - mu, d3 = v.w - mu;
  float sq = wave_sum(d0 * d0 + d1 * d1 + d2 * d2 + d3 * d3);
  float rs = rsqrtf(sq * (1.f / D_) + EPS_);
  float4 g  = *(const float4*)&gamma[b * D_ + c];
  float4 be = *(const float4*)&beta[b * D_ + c];
  float a0 = g.x * (d0 * rs) + be.x;
  float a1 = g.y * (d1 * rs) + be.y;
  float a2 = g.z * (d2 * rs) + be.z;
  float a3 = g.w * (d3 * rs) + be.w;
  float sum2 = wave_sum(a0 + a1 + a2 + a3);
  float mu2 = sum2 * (1.f / D_);
  float e0 = a0 - mu2, e1 = a1 - mu2, e2 = a2 - mu2, e3 = a3 - mu2;
  float sq2 = wave_sum(e0 * e0 + e1 * e1 + e2 * e2 + e3 * e3);
  float rs2 = rsqrtf(sq2 * (1.f / D_) + EPS_);
  float4 w  = *(const float4*)&lnw[c];
  float4 bb = *(const float4*)&lnb[c];
  float4 o;
  o.x = e0 * rs2 * w.x + bb.x;
  o.y = e1 * rs2 * w.y + bb.y;
  o.z = e2 * rs2 * w.z + bb.z;
  o.w = e3 * rs2 * w.w + bb.w;
  *(float4*)&out[(size_t)r * D_ + c] = o;
}

// ---------------- fp32 tiled GEMM: C[M,Nc] = A[M,K] @ W[Nc,K]^T (+bias)(+epi) ----------------
template <int EPI>
__global__ __launch_bounds__(256) void gemm_bt_kernel(
    const float* __restrict__ A, const float* __restrict__ Wt,
    const float* __restrict__ bias, const float* __restrict__ R,
    float* __restrict__ C, int M, int Nc, int K) {
  __shared__ __align__(16) float As[16][68];
  __shared__ __align__(16) float Bs[16][68];
  const int bm = blockIdx.y * 64;
  const int bn = blockIdx.x * 64;
  const int t = threadIdx.x;
  const int tx = t & 15, ty = t >> 4;
  const int lr = t >> 2;
  const int lk = (t & 3) << 2;
  float acc[4][4] = {};
  const float* Aload = A + (size_t)(bm + lr) * K + lk;
  const float* Wload = Wt + (size_t)(bn + lr) * K + lk;
  for (int k0 = 0; k0 < K; k0 += 16) {
    __syncthreads();
    float4 av = *(const float4*)(Aload + k0);
    float4 wv = *(const float4*)(Wload + k0);
    As[lk + 0][lr] = av.x; As[lk + 1][lr] = av.y;
    As[lk + 2][lr] = av.z; As[lk + 3][lr] = av.w;
    Bs[lk + 0][lr] = wv.x; Bs[lk + 1][lr] = wv.y;
    Bs[lk + 2][lr] = wv.z; Bs[lk + 3][lr] = wv.w;
    __syncthreads();
#pragma unroll
    for (int kk = 0; kk < 16; ++kk) {
      const float4 a = *(const float4*)&As[kk][ty << 2];
      const float4 b = *(const float4*)&Bs[kk][tx << 2];
      acc[0][0] += a.x * b.x; acc[0][1] += a.x * b.y; acc[0][2] += a.x * b.z; acc[0][3] += a.x * b.w;
      acc[1][0] += a.y * b.x; acc[1][1] += a.y * b.y; acc[1][2] += a.y * b.z; acc[1][3] += a.y * b.w;
      acc[2][0] += a.z * b.x; acc[2][1] += a.z * b.y; acc[2][2] += a.z * b.z; acc[2][3] += a.z * b.w;
      acc[3][0] += a.w * b.x; acc[3][1] += a.w * b.y; acc[3][2] += a.w * b.z; acc[3][3] += a.w * b.w;
    }
  }
#pragma unroll
  for (int i = 0; i < 4; ++i) {
    int row = bm + (ty << 2) + i;
    size_t base = (size_t)row * Nc + bn + (tx << 2);
#pragma unroll
    for (int j = 0; j < 4; ++j) {
      float v = acc[i][j];
      if (bias) v += bias[bn + (tx << 2) + j];
      if (EPI == 1) v = 0.5f * v * (1.f + erff(v * 0.7071067811865476f));
      if (EPI == 2) v += R[base + j];
      C[base + j] = v;
    }
  }
}

// ---------------- split-bf16 MFMA flash attention ----------------
// Block = 256 thr = 4 waves; one (b,h), 64 q-rows (16 per wave).
// Swapped QK^T: S^T = K@Q^T via mfma(A=K, B=Q^T); PV: O^T = V^T@P^T.
// fp32 accuracy via x = hi + lo bf16 split, 3 MFMAs per product.
__global__ __launch_bounds__(256) void attn_kernel(
    const float* __restrict__ qkv, float* __restrict__ ao) {
  __shared__ __align__(16) unsigned short Kh[64][40];   // [key][dim] pad->80B
  __shared__ __align__(16) unsigned short Kl[64][40];
  __shared__ __align__(16) unsigned short VTh[32][72];  // [dim][key] pad->144B
  __shared__ __align__(16) unsigned short VTl[32][72];
  __shared__ __align__(16) unsigned short Ph[4][16][72];  // per-wave [q][key]
  __shared__ __align__(16) unsigned short Pl[4][16][72];

  const int t = threadIdx.x;
  const int w = t >> 6;        // wave 0..3
  const int l = t & 63;
  const int lq = l & 15;       // q index (N col of both MFMAs)
  const int g = l >> 4;        // 0..3
  const int qt = blockIdx.x, h = blockIdx.y, b = blockIdx.z;

  // scores pre-scaled by log2(e)/sqrt(32) so softmax runs in exp2 domain
  const float QS = 0.2550332772677823f;

  // Q fragment (B operand of S^T): lane holds Q[q=lq][dims g*8..g*8+7]
  bf16x8 qh, ql;
  {
    const size_t rowq =
        ((size_t)(b * S_ + qt * 64 + w * 16 + lq)) * 768 + h * DH_ + g * 8;
    float4 qa = *(const float4*)&qkv[rowq];
    float4 qb = *(const float4*)&qkv[rowq + 4];
    float qf[8] = {qa.x, qa.y, qa.z, qa.w, qb.x, qb.y, qb.z, qb.w};
#pragma unroll
    for (int j = 0; j < 8; ++j) {
      float f = qf[j] * QS;
      unsigned short hi = f2bf(f);
      qh[j] = (short)hi;
      ql[j] = (short)f2bf(f - bf2f(hi));
    }
  }

  f32x4 oacc[2];
  oacc[0] = (f32x4){0.f, 0.f, 0.f, 0.f};
  oacc[1] = (f32x4){0.f, 0.f, 0.f, 0.f};
  float mrun = -1e30f, lrun = 0.f;

  const int key_s = t >> 2;   // staging: key 0..63
  const int dg = t & 3;       // staging: dim group of 8

  for (int kt = 0; kt < 16; ++kt) {
    __syncthreads();
    // ---- stage K (row-major) and V^T (transposed), hi+lo bf16 ----
    {
      const size_t rowb =
          ((size_t)(b * S_ + kt * 64 + key_s)) * 768 + h * DH_ + dg * 8;
      float4 ka = *(const float4*)&qkv[rowb + 256];
      float4 kb = *(const float4*)&qkv[rowb + 260];
      float4 va = *(const float4*)&qkv[rowb + 512];
      float4 vb = *(const float4*)&qkv[rowb + 516];
      float kf[8] = {ka.x, ka.y, ka.z, ka.w, kb.x, kb.y, kb.z, kb.w};
      float vf[8] = {va.x, va.y, va.z, va.w, vb.x, vb.y, vb.z, vb.w};
      unsigned short khi[8], klo[8];
#pragma unroll
      for (int j = 0; j < 8; ++j) {
        khi[j] = f2bf(kf[j]);
        klo[j] = f2bf(kf[j] - bf2f(khi[j]));
      }
      ushort4 h0, h1, l0, l1;
      h0.x = khi[0]; h0.y = khi[1]; h0.z = khi[2]; h0.w = khi[3];
      h1.x = khi[4]; h1.y = khi[5]; h1.z = khi[6]; h1.w = khi[7];
      l0.x = klo[0]; l0.y = klo[1]; l0.z = klo[2]; l0.w = klo[3];
      l1.x = klo[4]; l1.y = klo[5]; l1.z = klo[6]; l1.w = klo[7];
      *(ushort4*)&Kh[key_s][dg * 8] = h0;
      *(ushort4*)&Kh[key_s][dg * 8 + 4] = h1;
      *(ushort4*)&Kl[key_s][dg * 8] = l0;
      *(ushort4*)&Kl[key_s][dg * 8 + 4] = l1;
#pragma unroll
      for (int j = 0; j < 8; ++j) {
        unsigned short vh = f2bf(vf[j]);
        VTh[dg * 8 + j][key_s] = vh;
        VTl[dg * 8 + j][key_s] = f2bf(vf[j] - bf2f(vh));
      }
    }
    __syncthreads();

    // ---- QK^T: S^T[key][q], 4 key-subtiles of 16 ----
    f32x4 s[4];
#pragma unroll
    for (int i = 0; i < 4; ++i) {
      bf16x8 kfh = *(const bf16x8*)&Kh[i * 16 + lq][g * 8];
      bf16x8 kfl = *(const bf16x8*)&Kl[i * 16 + lq][g * 8];
      f32x4 c = (f32x4){0.f, 0.f, 0.f, 0.f};
      c = __builtin_amdgcn_mfma_f32_16x16x32_bf16(kfh, qh, c, 0, 0, 0);
      c = __builtin_amdgcn_mfma_f32_16x16x32_bf16(kfh, ql, c, 0, 0, 0);
      c = __builtin_amdgcn_mfma_f32_16x16x32_bf16(kfl, qh, c, 0, 0, 0);
      s[i] = c;
    }

    // ---- online softmax (lane owns q=lq; its 16 keys = 16i+4g+r) ----
    float pm = -1e30f;
#pragma unroll
    for (int i = 0; i < 4; ++i) {
#pragma unroll
      for (int r = 0; r < 4; ++r) pm = fmaxf(pm, s[i][r]);
    }
    pm = fmaxf(pm, __shfl_xor(pm, 16, 64));
    pm = fmaxf(pm, __shfl_xor(pm, 32, 64));
    float mnew = fmaxf(mrun, pm);
    float rfac = exp2f(mrun - mnew);
    mrun = mnew;
    oacc[0] *= rfac;
    oacc[1] *= rfac;
    float lsum = 0.f;
#pragma unroll
    for (int i = 0; i < 4; ++i) {
      ushort4 hv, lv;
      unsigned short hr[4], lr4[4];
#pragma unroll
      for (int r = 0; r < 4; ++r) {
        float p = exp2f(s[i][r] - mnew);
        lsum += p;
        unsigned short ph = f2bf(p);
        hr[r] = ph;
        lr4[r] = f2bf(p - bf2f(ph));
      }
      hv.x = hr[0]; hv.y = hr[1]; hv.z = hr[2]; hv.w = hr[3];
      lv.x = lr4[0]; lv.y = lr4[1]; lv.z = lr4[2]; lv.w = lr4[3];
      *(ushort4*)&Ph[w][lq][i * 16 + g * 4] = hv;
      *(ushort4*)&Pl[w][lq][i * 16 + g * 4] = lv;
    }
    lsum += __shfl_xor(lsum, 16, 64);
    lsum += __shfl_xor(lsum, 32, 64);
    lrun = lrun * rfac + lsum;

    // ---- PV: O^T[dim][q] += V^T @ P^T (per-wave P buffer, no barrier) ----
#pragma unroll
    for (int kh2 = 0; kh2 < 2; ++kh2) {
      bf16x8 pb = *(const bf16x8*)&Ph[w][lq][kh2 * 32 + g * 8];
      bf16x8 pl = *(const bf16x8*)&Pl[w][lq][kh2 * 32 + g * 8];
#pragma unroll
      for (int d = 0; d < 2; ++d) {
        bf16x8 vh = *(const bf16x8*)&VTh[d * 16 + lq][kh2 * 32 + g * 8];
        bf16x8 vl = *(const bf16x8*)&VTl[d * 16 + lq][kh2 * 32 + g * 8];
        oacc[d] = __builtin_amdgcn_mfma_f32_16x16x32_bf16(vh, pb, oacc[d], 0, 0, 0);
        oacc[d] = __builtin_amdgcn_mfma_f32_16x16x32_bf16(vh, pl, oacc[d], 0, 0, 0);
        oacc[d] = __builtin_amdgcn_mfma_f32_16x16x32_bf16(vl, pb, oacc[d], 0, 0, 0);
      }
    }
  }

  // ---- epilogue: lane holds O^T[dims d*16+4g+r][q=lq] ----
  float inv = 1.f / lrun;
  const size_t orow =
      ((size_t)(b * S_ + qt * 64 + w * 16 + lq)) * D_ + h * DH_;
#pragma unroll
  for (int d = 0; d < 2; ++d) {
    float4 ov;
    ov.x = oacc[d][0] * inv;
    ov.y = oacc[d][1] * inv;
    ov.z = oacc[d][2] * inv;
    ov.w = oacc[d][3] * inv;
    *(float4*)&ao[orow + d * 16 + g * 4] = ov;
  }
}

// ---------------- a_src/a_dst: per-node dots ----------------
__global__ __launch_bounds__(256) void adot_kernel(
    const float* __restrict__ h, const float* __restrict__ att_src,
    const float* __restrict__ att_dst, float* __restrict__ a_src,
    float* __restrict__ a_dst) {
  int wid = threadIdx.x >> 6, lane = threadIdx.x & 63;
  int n = blockIdx.x * 4 + wid;
  const int c = lane << 2;
  float4 hv = *(const float4*)&h[(size_t)n * D_ + c];
  float4 as = *(const float4*)&att_src[c];
  float4 ad = *(const float4*)&att_dst[c];
  float s = hv.x * as.x + hv.y * as.y + hv.z * as.z + hv.w * as.w;
  float d = hv.x * ad.x + hv.y * ad.y + hv.z * ad.z + hv.w * ad.w;
  s = wave_sum(s);
  d = wave_sum(d);
  if (lane == 0) { a_src[n] = s; a_dst[n] = d; }
}

// ---------------- GAT CSR build ----------------
__global__ __launch_bounds__(256) void hist_kernel(
    const int* __restrict__ e_dst, int* __restrict__ counts) {
  int i = blockIdx.x * 256 + threadIdx.x;
  if (i >= ETOT_) return;
  int dst = (i < E_) ? e_dst[i] : (i - E_);
  atomicAdd(&counts[dst], 1);
}

__global__ __launch_bounds__(1024) void scan_kernel(
    const int* __restrict__ counts, int* __restrict__ offsets,
    int* __restrict__ cursor) {
  __shared__ int sums[1024];
  const int t = threadIdx.x;
  int local[16];
  int s = 0;
#pragma unroll
  for (int i = 0; i < 16; ++i) { local[i] = s; s += counts[t * 16 + i]; }
  sums[t] = s;
  __syncthreads();
  for (int off = 1; off < 1024; off <<= 1) {
    int v = (t >= off) ? sums[t - off] : 0;
    __syncthreads();
    sums[t] += v;
    __syncthreads();
  }
  int base = (t > 0) ? sums[t - 1] : 0;
#pragma unroll
  for (int i = 0; i < 16; ++i) {
    int o = base + local[i];
    offsets[t * 16 + i] = o;
    cursor[t * 16 + i] = o;
  }
  if (t == 1023) offsets[N_] = sums[1023];
}

__global__ __launch_bounds__(256) void scatter_kernel(
    const int* __restrict__ e_src, const int* __restrict__ e_dst,
    int* __restrict__ cursor, int* __restrict__ csr_src) {
  int i = blockIdx.x * 256 + threadIdx.x;
  if (i >= ETOT_) return;
  int s = (i < E_) ? e_src[i] : (i - E_);
  int d = (i < E_) ? e_dst[i] : (i - E_);
  int slot = atomicAdd(&cursor[d], 1);
  csr_src[slot] = s;
}

// ---------------- GAT aggregate + bias + residual + gLN (one wave per node) ----------------
__global__ __launch_bounds__(256) void gat_ln_kernel(
    const float* __restrict__ h, const float* __restrict__ a_src,
    const float* __restrict__ a_dst, const int* __restrict__ offsets,
    const int* __restrict__ csr_src, const float* __restrict__ gat_bias,
    const float* __restrict__ x1, const float* __restrict__ gln_w,
    const float* __restrict__ gln_b, float* __restrict__ x2) {
  int wid = threadIdx.x >> 6, lane = threadIdx.x & 63;
  int n = blockIdx.x * 4 + wid;
  const int c = lane << 2;
  int beg = offsets[n], end = offsets[n + 1];
  float adn = a_dst[n];
  float m = -1e30f;
  for (int j = beg + lane; j < end; j += 64) {
    float e = a_src[csr_src[j]] + adn;
    e = (e >= 0.f) ? e : 0.2f * e;
    m = fmaxf(m, e);
  }
  m = wave_max(m);
  float z = 0.f;
  float ac0 = 0.f, ac1 = 0.f, ac2 = 0.f, ac3 = 0.f;
  for (int j0 = beg; j0 < end; j0 += 64) {
    int j = j0 + lane;
    float wgt = 0.f;
    int sidx = 0;
    if (j < end) {
      sidx = csr_src[j];
      float e = a_src[sidx] + adn;
      e = (e >= 0.f) ? e : 0.2f * e;
      wgt = __expf(e - m);
    }
    z += wgt;
    int cnt = min(64, end - j0);
    for (int jj = 0; jj < cnt; ++jj) {
      float ww = __shfl(wgt, jj, 64);
      int ss = __shfl(sidx, jj, 64);
      float4 hv = *(const float4*)&h[(size_t)ss * D_ + c];
      ac0 += ww * hv.x; ac1 += ww * hv.y; ac2 += ww * hv.z; ac3 += ww * hv.w;
    }
  }
  z = wave_sum(z);
  float inv = 1.f / z;
  float4 bv = *(const float4*)&gat_bias[c];
  float4 xv = *(const float4*)&x1[(size_t)n * D_ + c];
  float v0 = ac0 * inv + bv.x + xv.x;
  float v1 = ac1 * inv + bv.y + xv.y;
  float v2 = ac2 * inv + bv.z + xv.z;
  float v3 = ac3 * inv + bv.w + xv.w;
  float sum = wave_sum(v0 + v1 + v2 + v3);
  float mu = sum * (1.f / D_);
  float d0 = v0 - mu, d1 = v1 - mu, d2 = v2 - mu, d3 = v3 - mu;
  float sq = wave_sum(d0 * d0 + d1 * d1 + d2 * d2 + d3 * d3);
  float rs = rsqrtf(sq * (1.f / D_) + EPS_);
  float4 w4 = *(const float4*)&gln_w[c];
  float4 b4 = *(const float4*)&gln_b[c];
  float4 o;
  o.x = d0 * rs * w4.x + b4.x;
  o.y = d1 * rs * w4.y + b4.y;
  o.z = d2 * rs * w4.z + b4.z;
  o.w = d3 * rs * w4.w + b4.w;
  *(float4*)&x2[(size_t)n * D_ + c] = o;
}

// ---------------- launch ----------------
extern "C" void kernel_launch(void* const* d_in, const int* in_sizes, int n_in,
                              void* d_out, int out_size, void* d_ws,
                              size_t ws_size, hipStream_t stream) {
  const float* x         = (const float*)d_in[0];
  const float* prop_cond = (const float*)d_in[1];
  const int*   edges     = (const int*)d_in[2];
  const float* a1gw = (const float*)d_in[3];
  const float* a1gb = (const float*)d_in[4];
  const float* a1bw = (const float*)d_in[5];
  const float* a1bb = (const float*)d_in[6];
  const float* a2gw = (const float*)d_in[7];
  const float* a2gb = (const float*)d_in[8];
  const float* a2bw = (const float*)d_in[9];
  const float* a2bb = (const float*)d_in[10];
  const float* ln1w = (const float*)d_in[11];
  const float* ln1b = (const float*)d_in[12];
  const float* ln2w = (const float*)d_in[13];
  const float* ln2b = (const float*)d_in[14];
  const float* glnw = (const float*)d_in[15];
  const float* glnb = (const float*)d_in[16];
  const float* ipw  = (const float*)d_in[17];
  const float* ipb  = (const float*)d_in[18];
  const float* opw  = (const float*)d_in[19];
  const float* opb  = (const float*)d_in[20];
  const float* f1w  = (const float*)d_in[21];
  const float* f1b  = (const float*)d_in[22];
  const float* f2w  = (const float*)d_in[23];
  const float* f2b  = (const float*)d_in[24];
  const float* gatw = (const float*)d_in[25];
  const float* gats = (const float*)d_in[26];
  const float* gatd = (const float*)d_in[27];
  const float* gatb = (const float*)d_in[28];
  float* out = (float*)d_out;

  const int* e_src = edges;
  const int* e_dst = edges + E_;

  float* W = (float*)d_ws;
  const size_t F_BIG = 0;
  const size_t F_XN  = F_BIG + 16777216;
  const size_t F_X1  = F_XN + 4194304;
  const size_t F_H   = F_X1 + 4194304;
  const size_t F_X2  = F_H + 4194304;
  const size_t F_GB  = F_X2 + 4194304;
  const size_t F_AS  = F_GB + 16384;
  const size_t F_AD  = F_AS + N_;
  const size_t F_INT = F_AD + N_;
  float* buf_big = W + F_BIG;
  float* buf_xn  = W + F_XN;
  float* buf_x1  = W + F_X1;
  float* buf_h   = W + F_H;
  float* buf_x2  = W + F_X2;
  float* gamma1  = W + F_GB;
  float* beta1   = gamma1 + 4096;
  float* gamma2  = beta1 + 4096;
  float* beta2   = gamma2 + 4096;
  float* a_src   = W + F_AS;
  float* a_dst   = W + F_AD;
  int* counts  = (int*)(W + F_INT);
  int* offsets = counts + N_;
  int* cursor  = offsets + N_ + 1;
  int* csr_src = cursor + N_;

  hipMemsetAsync(counts, 0, N_ * sizeof(int), stream);

  gamma_beta_kernel<<<16, 256, 0, stream>>>(prop_cond, a1gw, a1gb, a1bw, a1bb,
                                            a2gw, a2gb, a2bw, a2bb, gamma1,
                                            beta1, gamma2, beta2);
  adaln_kernel<<<N_ / 4, 256, 0, stream>>>(x, gamma1, beta1, ln1w, ln1b, buf_xn);
  gemm_bt_kernel<0><<<dim3(12, 256), 256, 0, stream>>>(buf_xn, ipw, ipb, nullptr,
                                                       buf_big, N_, 768, 256);
  attn_kernel<<<dim3(16, 8, 16), 256, 0, stream>>>(buf_big, buf_xn);
  gemm_bt_kernel<2><<<dim3(4, 256), 256, 0, stream>>>(buf_xn, opw, opb, x,
                                                      buf_x1, N_, 256, 256);
  gemm_bt_kernel<0><<<dim3(4, 256), 256, 0, stream>>>(buf_x1, gatw, nullptr,
                                                      nullptr, buf_h, N_, 256, 256);
  adot_kernel<<<N_ / 4, 256, 0, stream>>>(buf_h, gats, gatd, a_src, a_dst);
  hist_kernel<<<(ETOT_ + 255) / 256, 256, 0, stream>>>(e_dst, counts);
  scan_kernel<<<1, 1024, 0, stream>>>(counts, offsets, cursor);
  scatter_kernel<<<(ETOT_ + 255) / 256, 256, 0, stream>>>(e_src, e_dst, cursor,
                                                          csr_src);
  gat_ln_kernel<<<N_ / 4, 256, 0, stream>>>(buf_h, a_src, a_dst, offsets,
                                            csr_src, gatb, buf_x1, glnw, glnb,
                                            buf_x2);
  adaln_kernel<<<N_ / 4, 256, 0, stream>>>(buf_x2, gamma2, beta2, ln2w, ln2b,
                                           buf_xn);
  gemm_bt_kernel<1><<<dim3(16, 256), 256, 0, stream>>>(buf_xn, f1w, f1b, nullptr,
                                                       buf_big, N_, DFF_, 256);
  gemm_bt_kernel<2><<<dim3(4, 256), 256, 0, stream>>>(buf_big, f2w, f2b, buf_x2,
                                                      out, N_, 256, DFF_);
}

// Round 6
// 534.541 us; speedup vs baseline: 2.0503x; 1.4754x over previous
//
#include <hip/hip_runtime.h>
#include <cmath>

#define B_    16
#define S_    1024
#define D_    256
#define H_    8
#define DH_   32
#define DFF_  1024
#define PDIM_ 64
#define N_    (B_ * S_)      // 16384
#define E_    262144
#define ETOT_ (E_ + N_)      // 278528
#define EPS_  1e-5f

typedef __attribute__((ext_vector_type(8))) short bf16x8;
typedef __attribute__((ext_vector_type(4))) float f32x4;

// ---------------- wave helpers ----------------
__device__ __forceinline__ float wave_sum(float v) {
#pragma unroll
  for (int m = 1; m < 64; m <<= 1) v += __shfl_xor(v, m, 64);
  return v;
}
__device__ __forceinline__ float wave_max(float v) {
#pragma unroll
  for (int m = 1; m < 64; m <<= 1) v = fmaxf(v, __shfl_xor(v, m, 64));
  return v;
}

// bf16 split helpers (RNE)
__device__ __forceinline__ unsigned short f2bf(float f) {
  unsigned int u = __float_as_uint(f);
  unsigned int r = u + 0x7fffu + ((u >> 16) & 1u);
  return (unsigned short)(r >> 16);
}
__device__ __forceinline__ float bf2f(unsigned short s) {
  return __uint_as_float(((unsigned int)s) << 16);
}
__device__ __forceinline__ void split4(float4 v, ushort4& hi, ushort4& lo) {
  unsigned short h;
  h = f2bf(v.x); hi.x = h; lo.x = f2bf(v.x - bf2f(h));
  h = f2bf(v.y); hi.y = h; lo.y = f2bf(v.y - bf2f(h));
  h = f2bf(v.z); hi.z = h; lo.z = f2bf(v.z - bf2f(h));
  h = f2bf(v.w); hi.w = h; lo.w = f2bf(v.w - bf2f(h));
}

// ---------------- gamma/beta for both AdaLNs ----------------
__global__ __launch_bounds__(256) void gamma_beta_kernel(
    const float* __restrict__ pc,
    const float* __restrict__ g1w, const float* __restrict__ g1b,
    const float* __restrict__ b1w, const float* __restrict__ b1b,
    const float* __restrict__ g2w, const float* __restrict__ g2b,
    const float* __restrict__ b2w, const float* __restrict__ b2b,
    float* __restrict__ gamma1, float* __restrict__ beta1,
    float* __restrict__ gamma2, float* __restrict__ beta2) {
  int i = blockIdx.x * 256 + threadIdx.x;
  if (i >= B_ * D_) return;
  int b = i >> 8, d = i & 255;
  const float* p = pc + b * PDIM_;
  float s1 = 0.f, s2 = 0.f, s3 = 0.f, s4 = 0.f;
#pragma unroll 8
  for (int k = 0; k < PDIM_; ++k) {
    float pv = p[k];
    s1 += pv * g1w[d * PDIM_ + k];
    s2 += pv * b1w[d * PDIM_ + k];
    s3 += pv * g2w[d * PDIM_ + k];
    s4 += pv * b2w[d * PDIM_ + k];
  }
  gamma1[i] = s1 + g1b[d];
  beta1[i]  = s2 + b1b[d];
  gamma2[i] = s3 + g2b[d];
  beta2[i]  = s4 + b2b[d];
}

// ---------------- AdaLN (plain LN -> gamma*xhat+beta -> LN(w,b)) ----------------
__global__ __launch_bounds__(256) void adaln_kernel(
    const float* __restrict__ x, const float* __restrict__ gamma,
    const float* __restrict__ beta, const float* __restrict__ lnw,
    const float* __restrict__ lnb, float* __restrict__ out) {
  int wid = threadIdx.x >> 6, lane = threadIdx.x & 63;
  int r = blockIdx.x * 4 + wid;
  int b = r >> 10;
  const int c = lane << 2;
  float4 v = *(const float4*)&x[(size_t)r * D_ + c];
  float sum = wave_sum(v.x + v.y + v.z + v.w);
  float mu = sum * (1.f / D_);
  float d0 = v.x - mu, d1 = v.y - mu, d2 = v.z - mu, d3 = v.w - mu;
  float sq = wave_sum(d0 * d0 + d1 * d1 + d2 * d2 + d3 * d3);
  float rs = rsqrtf(sq * (1.f / D_) + EPS_);
  float4 g  = *(const float4*)&gamma[b * D_ + c];
  float4 be = *(const float4*)&beta[b * D_ + c];
  float a0 = g.x * (d0 * rs) + be.x;
  float a1 = g.y * (d1 * rs) + be.y;
  float a2 = g.z * (d2 * rs) + be.z;
  float a3 = g.w * (d3 * rs) + be.w;
  float sum2 = wave_sum(a0 + a1 + a2 + a3);
  float mu2 = sum2 * (1.f / D_);
  float e0 = a0 - mu2, e1 = a1 - mu2, e2 = a2 - mu2, e3 = a3 - mu2;
  float sq2 = wave_sum(e0 * e0 + e1 * e1 + e2 * e2 + e3 * e3);
  float rs2 = rsqrtf(sq2 * (1.f / D_) + EPS_);
  float4 w  = *(const float4*)&lnw[c];
  float4 bb = *(const float4*)&lnb[c];
  float4 o;
  o.x = e0 * rs2 * w.x + bb.x;
  o.y = e1 * rs2 * w.y + bb.y;
  o.z = e2 * rs2 * w.z + bb.z;
  o.w = e3 * rs2 * w.w + bb.w;
  *(float4*)&out[(size_t)r * D_ + c] = o;
}

// ---------------- split-bf16 MFMA GEMM: C[M,Nc] = A[M,K]@W[Nc,K]^T ----------------
// EPI: 0 none, 1 exact GELU, 2 +R. MS: 4 -> BM=128 tile, 2 -> BM=64 tile. BN=128.
// 4 waves in 2x2; fp32->hi/lo bf16 reg-staged; next-tile global loads issued
// before the compute barrier (latency hidden under MFMA).
template <int EPI, int MS>
__global__ __launch_bounds__(256) void gemm_mfma_kernel(
    const float* __restrict__ A, const float* __restrict__ Wt,
    const float* __restrict__ bias, const float* __restrict__ R,
    float* __restrict__ C, int M, int Nc, int K) {
  __shared__ __align__(16) unsigned short Ah[MS * 32][40];
  __shared__ __align__(16) unsigned short Al[MS * 32][40];
  __shared__ __align__(16) unsigned short Bh[128][40];
  __shared__ __align__(16) unsigned short Bl[128][40];
  const int t = threadIdx.x;
  const int w = t >> 6, l = t & 63;
  const int lr = l & 15, lg = l >> 4;
  const int bm = blockIdx.y * (MS * 32), bn = blockIdx.x * 128;
  // staging: A has MS*32 rows; each thread loads NA float4s of one row
  constexpr int SA = (MS == 4) ? 1 : 2;
  constexpr int NA = (MS == 4) ? 4 : 2;
  const int sra = t >> SA;
  const int ska = (t & ((1 << SA) - 1)) * (NA * 4);
  const int srb = t >> 1;
  const int skb = (t & 1) * 16;
  const float* Ap = A + (size_t)(bm + sra) * K + ska;
  const float* Bp = Wt + (size_t)(bn + srb) * K + skb;

  f32x4 acc[MS][4];
#pragma unroll
  for (int i = 0; i < MS; ++i)
#pragma unroll
    for (int j = 0; j < 4; ++j) acc[i][j] = (f32x4){0.f, 0.f, 0.f, 0.f};

  float4 ra[NA], rb[4];
#pragma unroll
  for (int c = 0; c < NA; ++c) ra[c] = *(const float4*)(Ap + c * 4);
#pragma unroll
  for (int c = 0; c < 4; ++c) rb[c] = *(const float4*)(Bp + c * 4);

  const int nk = K >> 5;
  for (int kt = 0; kt < nk; ++kt) {
    __syncthreads();
#pragma unroll
    for (int c = 0; c < NA; ++c) {
      ushort4 h4, l4;
      split4(ra[c], h4, l4);
      *(ushort4*)&Ah[sra][ska + c * 4] = h4;
      *(ushort4*)&Al[sra][ska + c * 4] = l4;
    }
#pragma unroll
    for (int c = 0; c < 4; ++c) {
      ushort4 h4, l4;
      split4(rb[c], h4, l4);
      *(ushort4*)&Bh[srb][skb + c * 4] = h4;
      *(ushort4*)&Bl[srb][skb + c * 4] = l4;
    }
    if (kt + 1 < nk) {
      Ap += 32;
      Bp += 32;
#pragma unroll
      for (int c = 0; c < NA; ++c) ra[c] = *(const float4*)(Ap + c * 4);
#pragma unroll
      for (int c = 0; c < 4; ++c) rb[c] = *(const float4*)(Bp + c * 4);
    }
    __syncthreads();
    bf16x8 bhj[4], blj[4];
#pragma unroll
    for (int j = 0; j < 4; ++j) {
      bhj[j] = *(const bf16x8*)&Bh[(w & 1) * 64 + j * 16 + lr][lg * 8];
      blj[j] = *(const bf16x8*)&Bl[(w & 1) * 64 + j * 16 + lr][lg * 8];
    }
#pragma unroll
    for (int i = 0; i < MS; ++i) {
      bf16x8 ahi = *(const bf16x8*)&Ah[(w >> 1) * (MS * 16) + i * 16 + lr][lg * 8];
      bf16x8 ali = *(const bf16x8*)&Al[(w >> 1) * (MS * 16) + i * 16 + lr][lg * 8];
#pragma unroll
      for (int j = 0; j < 4; ++j) {
        acc[i][j] = __builtin_amdgcn_mfma_f32_16x16x32_bf16(ahi, bhj[j], acc[i][j], 0, 0, 0);
        acc[i][j] = __builtin_amdgcn_mfma_f32_16x16x32_bf16(ali, bhj[j], acc[i][j], 0, 0, 0);
        acc[i][j] = __builtin_amdgcn_mfma_f32_16x16x32_bf16(ahi, blj[j], acc[i][j], 0, 0, 0);
      }
    }
  }
  // epilogue: m = bm + (w>>1)*MS*16 + i*16 + lg*4 + r ; n = bn + (w&1)*64 + j*16 + lr
#pragma unroll
  for (int i = 0; i < MS; ++i) {
    const int m0 = bm + (w >> 1) * (MS * 16) + i * 16 + lg * 4;
#pragma unroll
    for (int j = 0; j < 4; ++j) {
      const int n = bn + (w & 1) * 64 + j * 16 + lr;
      const float bv = bias ? bias[n] : 0.f;
#pragma unroll
      for (int r = 0; r < 4; ++r) {
        const size_t idx = (size_t)(m0 + r) * Nc + n;
        float v = acc[i][j][r] + bv;
        if (EPI == 1) v = 0.5f * v * (1.f + erff(v * 0.7071067811865476f));
        if (EPI == 2) v += R[idx];
        C[idx] = v;
      }
    }
  }
}

// ---------------- split-bf16 MFMA flash attention ----------------
// Block = 4 waves; one (b,h); 256 q-rows/block (64 per wave, 4 subtiles of 16).
// K/V staged+split ONCE per 64-key tile, reused by 4 q-subtiles.
__global__ __launch_bounds__(256) void attn_kernel(
    const float* __restrict__ qkv, float* __restrict__ ao) {
  __shared__ __align__(16) unsigned short Kh[64][40];
  __shared__ __align__(16) unsigned short Kl[64][40];
  __shared__ __align__(16) unsigned short VTh[32][72];
  __shared__ __align__(16) unsigned short VTl[32][72];
  __shared__ __align__(16) unsigned short Ph[4][16][72];
  __shared__ __align__(16) unsigned short Pl[4][16][72];

  const int t = threadIdx.x;
  const int w = t >> 6;
  const int l = t & 63;
  const int lq = l & 15;
  const int g = l >> 4;
  const int qt = blockIdx.x, h = blockIdx.y, b = blockIdx.z;
  const int qbase = qt * 256 + w * 64;

  const float QS = 0.2550332772677823f;  // log2(e)/sqrt(32)

  bf16x8 qh[4], ql[4];
#pragma unroll
  for (int qs = 0; qs < 4; ++qs) {
    const size_t rowq =
        ((size_t)(b * S_ + qbase + qs * 16 + lq)) * 768 + h * DH_ + g * 8;
    float4 qa = *(const float4*)&qkv[rowq];
    float4 qb = *(const float4*)&qkv[rowq + 4];
    float qf[8] = {qa.x, qa.y, qa.z, qa.w, qb.x, qb.y, qb.z, qb.w};
#pragma unroll
    for (int j = 0; j < 8; ++j) {
      float f = qf[j] * QS;
      unsigned short hi = f2bf(f);
      qh[qs][j] = (short)hi;
      ql[qs][j] = (short)f2bf(f - bf2f(hi));
    }
  }

  f32x4 oacc[4][2];
  float mrun[4], lrun[4];
#pragma unroll
  for (int qs = 0; qs < 4; ++qs) {
    oacc[qs][0] = (f32x4){0.f, 0.f, 0.f, 0.f};
    oacc[qs][1] = (f32x4){0.f, 0.f, 0.f, 0.f};
    mrun[qs] = -1e30f;
    lrun[qs] = 0.f;
  }

  const int key_s = t >> 2;
  const int dg = t & 3;

  for (int kt = 0; kt < 16; ++kt) {
    __syncthreads();
    // ---- stage K (row-major) and V^T (transposed), hi+lo bf16 ----
    {
      const size_t rowb =
          ((size_t)(b * S_ + kt * 64 + key_s)) * 768 + h * DH_ + dg * 8;
      float4 ka = *(const float4*)&qkv[rowb + 256];
      float4 kb = *(const float4*)&qkv[rowb + 260];
      float4 va = *(const float4*)&qkv[rowb + 512];
      float4 vb = *(const float4*)&qkv[rowb + 516];
      ushort4 h0, h1, l0, l1;
      split4(ka, h0, l0);
      split4(kb, h1, l1);
      *(ushort4*)&Kh[key_s][dg * 8] = h0;
      *(ushort4*)&Kh[key_s][dg * 8 + 4] = h1;
      *(ushort4*)&Kl[key_s][dg * 8] = l0;
      *(ushort4*)&Kl[key_s][dg * 8 + 4] = l1;
      float vf[8] = {va.x, va.y, va.z, va.w, vb.x, vb.y, vb.z, vb.w};
#pragma unroll
      for (int j = 0; j < 8; ++j) {
        unsigned short vh = f2bf(vf[j]);
        VTh[dg * 8 + j][key_s] = vh;
        VTl[dg * 8 + j][key_s] = f2bf(vf[j] - bf2f(vh));
      }
    }
    __syncthreads();

    // hoisted K fragments (shared across the 4 q-subtiles)
    bf16x8 kfh[4], kfl[4];
#pragma unroll
    for (int i = 0; i < 4; ++i) {
      kfh[i] = *(const bf16x8*)&Kh[i * 16 + lq][g * 8];
      kfl[i] = *(const bf16x8*)&Kl[i * 16 + lq][g * 8];
    }

#pragma unroll
    for (int qs = 0; qs < 4; ++qs) {
      // ---- QK^T: S^T[key][q] ----
      f32x4 s[4];
#pragma unroll
      for (int i = 0; i < 4; ++i) {
        f32x4 c = (f32x4){0.f, 0.f, 0.f, 0.f};
        c = __builtin_amdgcn_mfma_f32_16x16x32_bf16(kfh[i], qh[qs], c, 0, 0, 0);
        c = __builtin_amdgcn_mfma_f32_16x16x32_bf16(kfh[i], ql[qs], c, 0, 0, 0);
        c = __builtin_amdgcn_mfma_f32_16x16x32_bf16(kfl[i], qh[qs], c, 0, 0, 0);
        s[i] = c;
      }
      // ---- online softmax (lane owns q=lq; keys 16i+4g+r) ----
      float pm = -1e30f;
#pragma unroll
      for (int i = 0; i < 4; ++i)
#pragma unroll
        for (int r = 0; r < 4; ++r) pm = fmaxf(pm, s[i][r]);
      pm = fmaxf(pm, __shfl_xor(pm, 16, 64));
      pm = fmaxf(pm, __shfl_xor(pm, 32, 64));
      float mnew = fmaxf(mrun[qs], pm);
      float rfac = exp2f(mrun[qs] - mnew);
      mrun[qs] = mnew;
      oacc[qs][0] *= rfac;
      oacc[qs][1] *= rfac;
      float lsum = 0.f;
#pragma unroll
      for (int i = 0; i < 4; ++i) {
        ushort4 hv, lv;
        unsigned short hr[4], lr4[4];
#pragma unroll
        for (int r = 0; r < 4; ++r) {
          float p = exp2f(s[i][r] - mnew);
          lsum += p;
          unsigned short ph = f2bf(p);
          hr[r] = ph;
          lr4[r] = f2bf(p - bf2f(ph));
        }
        hv.x = hr[0]; hv.y = hr[1]; hv.z = hr[2]; hv.w = hr[3];
        lv.x = lr4[0]; lv.y = lr4[1]; lv.z = lr4[2]; lv.w = lr4[3];
        *(ushort4*)&Ph[w][lq][i * 16 + g * 4] = hv;
        *(ushort4*)&Pl[w][lq][i * 16 + g * 4] = lv;
      }
      lsum += __shfl_xor(lsum, 16, 64);
      lsum += __shfl_xor(lsum, 32, 64);
      lrun[qs] = lrun[qs] * rfac + lsum;

      // ---- PV: O^T[dim][q] += V^T @ P^T ----
#pragma unroll
      for (int kh2 = 0; kh2 < 2; ++kh2) {
        bf16x8 pb = *(const bf16x8*)&Ph[w][lq][kh2 * 32 + g * 8];
        bf16x8 pl = *(const bf16x8*)&Pl[w][lq][kh2 * 32 + g * 8];
#pragma unroll
        for (int d = 0; d < 2; ++d) {
          bf16x8 vh = *(const bf16x8*)&VTh[d * 16 + lq][kh2 * 32 + g * 8];
          bf16x8 vl = *(const bf16x8*)&VTl[d * 16 + lq][kh2 * 32 + g * 8];
          oacc[qs][d] = __builtin_amdgcn_mfma_f32_16x16x32_bf16(vh, pb, oacc[qs][d], 0, 0, 0);
          oacc[qs][d] = __builtin_amdgcn_mfma_f32_16x16x32_bf16(vh, pl, oacc[qs][d], 0, 0, 0);
          oacc[qs][d] = __builtin_amdgcn_mfma_f32_16x16x32_bf16(vl, pb, oacc[qs][d], 0, 0, 0);
        }
      }
    }
  }

  // ---- epilogue: lane holds O^T[dims d*16+4g+r][q=lq] ----
#pragma unroll
  for (int qs = 0; qs < 4; ++qs) {
    float inv = 1.f / lrun[qs];
    const size_t orow =
        ((size_t)(b * S_ + qbase + qs * 16 + lq)) * D_ + h * DH_;
#pragma unroll
    for (int d = 0; d < 2; ++d) {
      float4 ov;
      ov.x = oacc[qs][d][0] * inv;
      ov.y = oacc[qs][d][1] * inv;
      ov.z = oacc[qs][d][2] * inv;
      ov.w = oacc[qs][d][3] * inv;
      *(float4*)&ao[orow + d * 16 + g * 4] = ov;
    }
  }
}

// ---------------- a_src/a_dst: per-node dots ----------------
__global__ __launch_bounds__(256) void adot_kernel(
    const float* __restrict__ h, const float* __restrict__ att_src,
    const float* __restrict__ att_dst, float* __restrict__ a_src,
    float* __restrict__ a_dst) {
  int wid = threadIdx.x >> 6, lane = threadIdx.x & 63;
  int n = blockIdx.x * 4 + wid;
  const int c = lane << 2;
  float4 hv = *(const float4*)&h[(size_t)n * D_ + c];
  float4 as = *(const float4*)&att_src[c];
  float4 ad = *(const float4*)&att_dst[c];
  float s = hv.x * as.x + hv.y * as.y + hv.z * as.z + hv.w * as.w;
  float d = hv.x * ad.x + hv.y * ad.y + hv.z * ad.z + hv.w * ad.w;
  s = wave_sum(s);
  d = wave_sum(d);
  if (lane == 0) { a_src[n] = s; a_dst[n] = d; }
}

// ---------------- GAT CSR build ----------------
__global__ __launch_bounds__(256) void hist_kernel(
    const int* __restrict__ e_dst, int* __restrict__ counts) {
  int i = blockIdx.x * 256 + threadIdx.x;
  if (i >= ETOT_) return;
  int dst = (i < E_) ? e_dst[i] : (i - E_);
  atomicAdd(&counts[dst], 1);
}

__global__ __launch_bounds__(1024) void scan_kernel(
    const int* __restrict__ counts, int* __restrict__ offsets,
    int* __restrict__ cursor) {
  __shared__ int sums[1024];
  const int t = threadIdx.x;
  int local[16];
  int s = 0;
#pragma unroll
  for (int i = 0; i < 16; ++i) { local[i] = s; s += counts[t * 16 + i]; }
  sums[t] = s;
  __syncthreads();
  for (int off = 1; off < 1024; off <<= 1) {
    int v = (t >= off) ? sums[t - off] : 0;
    __syncthreads();
    sums[t] += v;
    __syncthreads();
  }
  int base = (t > 0) ? sums[t - 1] : 0;
#pragma unroll
  for (int i = 0; i < 16; ++i) {
    int o = base + local[i];
    offsets[t * 16 + i] = o;
    cursor[t * 16 + i] = o;
  }
  if (t == 1023) offsets[N_] = sums[1023];
}

__global__ __launch_bounds__(256) void scatter_kernel(
    const int* __restrict__ e_src, const int* __restrict__ e_dst,
    int* __restrict__ cursor, int* __restrict__ csr_src) {
  int i = blockIdx.x * 256 + threadIdx.x;
  if (i >= ETOT_) return;
  int s = (i < E_) ? e_src[i] : (i - E_);
  int d = (i < E_) ? e_dst[i] : (i - E_);
  int slot = atomicAdd(&cursor[d], 1);
  csr_src[slot] = s;
}

// ---------------- GAT aggregate + bias + residual + gLN (one wave per node) ----------------
__global__ __launch_bounds__(256) void gat_ln_kernel(
    const float* __restrict__ h, const float* __restrict__ a_src,
    const float* __restrict__ a_dst, const int* __restrict__ offsets,
    const int* __restrict__ csr_src, const float* __restrict__ gat_bias,
    const float* __restrict__ x1, const float* __restrict__ gln_w,
    const float* __restrict__ gln_b, float* __restrict__ x2) {
  int wid = threadIdx.x >> 6, lane = threadIdx.x & 63;
  int n = blockIdx.x * 4 + wid;
  const int c = lane << 2;
  int beg = offsets[n], end = offsets[n + 1];
  float adn = a_dst[n];
  float m = -1e30f;
  for (int j = beg + lane; j < end; j += 64) {
    float e = a_src[csr_src[j]] + adn;
    e = (e >= 0.f) ? e : 0.2f * e;
    m = fmaxf(m, e);
  }
  m = wave_max(m);
  float z = 0.f;
  float ac0 = 0.f, ac1 = 0.f, ac2 = 0.f, ac3 = 0.f;
  for (int j0 = beg; j0 < end; j0 += 64) {
    int j = j0 + lane;
    float wgt = 0.f;
    int sidx = 0;
    if (j < end) {
      sidx = csr_src[j];
      float e = a_src[sidx] + adn;
      e = (e >= 0.f) ? e : 0.2f * e;
      wgt = __expf(e - m);
    }
    z += wgt;
    int cnt = min(64, end - j0);
    for (int jj = 0; jj < cnt; ++jj) {
      float ww = __shfl(wgt, jj, 64);
      int ss = __shfl(sidx, jj, 64);
      float4 hv = *(const float4*)&h[(size_t)ss * D_ + c];
      ac0 += ww * hv.x; ac1 += ww * hv.y; ac2 += ww * hv.z; ac3 += ww * hv.w;
    }
  }
  z = wave_sum(z);
  float inv = 1.f / z;
  float4 bv = *(const float4*)&gat_bias[c];
  float4 xv = *(const float4*)&x1[(size_t)n * D_ + c];
  float v0 = ac0 * inv + bv.x + xv.x;
  float v1 = ac1 * inv + bv.y + xv.y;
  float v2 = ac2 * inv + bv.z + xv.z;
  float v3 = ac3 * inv + bv.w + xv.w;
  float sum = wave_sum(v0 + v1 + v2 + v3);
  float mu = sum * (1.f / D_);
  float d0 = v0 - mu, d1 = v1 - mu, d2 = v2 - mu, d3 = v3 - mu;
  float sq = wave_sum(d0 * d0 + d1 * d1 + d2 * d2 + d3 * d3);
  float rs = rsqrtf(sq * (1.f / D_) + EPS_);
  float4 w4 = *(const float4*)&gln_w[c];
  float4 b4 = *(const float4*)&gln_b[c];
  float4 o;
  o.x = d0 * rs * w4.x + b4.x;
  o.y = d1 * rs * w4.y + b4.y;
  o.z = d2 * rs * w4.z + b4.z;
  o.w = d3 * rs * w4.w + b4.w;
  *(float4*)&x2[(size_t)n * D_ + c] = o;
}

// ---------------- launch ----------------
extern "C" void kernel_launch(void* const* d_in, const int* in_sizes, int n_in,
                              void* d_out, int out_size, void* d_ws,
                              size_t ws_size, hipStream_t stream) {
  const float* x         = (const float*)d_in[0];
  const float* prop_cond = (const float*)d_in[1];
  const int*   edges     = (const int*)d_in[2];
  const float* a1gw = (const float*)d_in[3];
  const float* a1gb = (const float*)d_in[4];
  const float* a1bw = (const float*)d_in[5];
  const float* a1bb = (const float*)d_in[6];
  const float* a2gw = (const float*)d_in[7];
  const float* a2gb = (const float*)d_in[8];
  const float* a2bw = (const float*)d_in[9];
  const float* a2bb = (const float*)d_in[10];
  const float* ln1w = (const float*)d_in[11];
  const float* ln1b = (const float*)d_in[12];
  const float* ln2w = (const float*)d_in[13];
  const float* ln2b = (const float*)d_in[14];
  const float* glnw = (const float*)d_in[15];
  const float* glnb = (const float*)d_in[16];
  const float* ipw  = (const float*)d_in[17];
  const float* ipb  = (const float*)d_in[18];
  const float* opw  = (const float*)d_in[19];
  const float* opb  = (const float*)d_in[20];
  const float* f1w  = (const float*)d_in[21];
  const float* f1b  = (const float*)d_in[22];
  const float* f2w  = (const float*)d_in[23];
  const float* f2b  = (const float*)d_in[24];
  const float* gatw = (const float*)d_in[25];
  const float* gats = (const float*)d_in[26];
  const float* gatd = (const float*)d_in[27];
  const float* gatb = (const float*)d_in[28];
  float* out = (float*)d_out;

  const int* e_src = edges;
  const int* e_dst = edges + E_;

  float* W = (float*)d_ws;
  const size_t F_BIG = 0;
  const size_t F_XN  = F_BIG + 16777216;
  const size_t F_X1  = F_XN + 4194304;
  const size_t F_H   = F_X1 + 4194304;
  const size_t F_X2  = F_H + 4194304;
  const size_t F_GB  = F_X2 + 4194304;
  const size_t F_AS  = F_GB + 16384;
  const size_t F_AD  = F_AS + N_;
  const size_t F_INT = F_AD + N_;
  float* buf_big = W + F_BIG;
  float* buf_xn  = W + F_XN;
  float* buf_x1  = W + F_X1;
  float* buf_h   = W + F_H;
  float* buf_x2  = W + F_X2;
  float* gamma1  = W + F_GB;
  float* beta1   = gamma1 + 4096;
  float* gamma2  = beta1 + 4096;
  float* beta2   = gamma2 + 4096;
  float* a_src   = W + F_AS;
  float* a_dst   = W + F_AD;
  int* counts  = (int*)(W + F_INT);
  int* offsets = counts + N_;
  int* cursor  = offsets + N_ + 1;
  int* csr_src = cursor + N_;

  hipMemsetAsync(counts, 0, N_ * sizeof(int), stream);

  gamma_beta_kernel<<<16, 256, 0, stream>>>(prop_cond, a1gw, a1gb, a1bw, a1bb,
                                            a2gw, a2gb, a2bw, a2bb, gamma1,
                                            beta1, gamma2, beta2);
  adaln_kernel<<<N_ / 4, 256, 0, stream>>>(x, gamma1, beta1, ln1w, ln1b, buf_xn);
  // QKV projection [16384,256]@[768,256]^T
  gemm_mfma_kernel<0, 4><<<dim3(6, 128), 256, 0, stream>>>(
      buf_xn, ipw, ipb, nullptr, buf_big, N_, 768, 256);
  attn_kernel<<<dim3(4, 8, 16), 256, 0, stream>>>(buf_big, buf_xn);
  // out_proj + residual(x)
  gemm_mfma_kernel<2, 2><<<dim3(2, 256), 256, 0, stream>>>(
      buf_xn, opw, opb, x, buf_x1, N_, 256, 256);
  // GAT h = x1 @ gat_w^T
  gemm_mfma_kernel<0, 2><<<dim3(2, 256), 256, 0, stream>>>(
      buf_x1, gatw, nullptr, nullptr, buf_h, N_, 256, 256);
  adot_kernel<<<N_ / 4, 256, 0, stream>>>(buf_h, gats, gatd, a_src, a_dst);
  hist_kernel<<<(ETOT_ + 255) / 256, 256, 0, stream>>>(e_dst, counts);
  scan_kernel<<<1, 1024, 0, stream>>>(counts, offsets, cursor);
  scatter_kernel<<<(ETOT_ + 255) / 256, 256, 0, stream>>>(e_src, e_dst, cursor,
                                                          csr_src);
  gat_ln_kernel<<<N_ / 4, 256, 0, stream>>>(buf_h, a_src, a_dst, offsets,
                                            csr_src, gatb, buf_x1, glnw, glnb,
                                            buf_x2);
  adaln_kernel<<<N_ / 4, 256, 0, stream>>>(buf_x2, gamma2, beta2, ln2w, ln2b,
                                           buf_xn);
  // FFN1 + GELU
  gemm_mfma_kernel<1, 4><<<dim3(8, 128), 256, 0, stream>>>(
      buf_xn, f1w, f1b, nullptr, buf_big, N_, DFF_, 256);
  // FFN2 + residual(x2)
  gemm_mfma_kernel<2, 2><<<dim3(2, 256), 256, 0, stream>>>(
      buf_big, f2w, f2b, buf_x2, out, N_, 256, DFF_);
}

// Round 8
// 491.936 us; speedup vs baseline: 2.2278x; 1.0866x over previous
//
#include <hip/hip_runtime.h>
#include <cmath>

#define B_    16
#define S_    1024
#define D_    256
#define H_    8
#define DH_   32
#define DFF_  1024
#define PDIM_ 64
#define N_    (B_ * S_)      // 16384
#define E_    262144
#define ETOT_ (E_ + N_)      // 278528
#define EPS_  1e-5f

typedef __attribute__((ext_vector_type(8))) short bf16x8;
typedef __attribute__((ext_vector_type(8))) unsigned short u16x8;
typedef __attribute__((ext_vector_type(4))) float f32x4;

// split-qkv buffer layout (ushort units), each array 4194304 elements:
// Qh at 0, Ql at 4194304, Kh at 8388608, Kl at 12582912, Vh at 16777216, Vl at 20971520
#define QKV_SEC 8388608
#define QKV_LO  4194304

// ---------------- wave helpers ----------------
__device__ __forceinline__ float wave_sum(float v) {
#pragma unroll
  for (int m = 1; m < 64; m <<= 1) v += __shfl_xor(v, m, 64);
  return v;
}
__device__ __forceinline__ float wave_max(float v) {
#pragma unroll
  for (int m = 1; m < 64; m <<= 1) v = fmaxf(v, __shfl_xor(v, m, 64));
  return v;
}

// bf16 split helpers (RNE)
__device__ __forceinline__ unsigned short f2bf(float f) {
  unsigned int u = __float_as_uint(f);
  unsigned int r = u + 0x7fffu + ((u >> 16) & 1u);
  return (unsigned short)(r >> 16);
}
__device__ __forceinline__ float bf2f(unsigned short s) {
  return __uint_as_float(((unsigned int)s) << 16);
}
__device__ __forceinline__ void split4(float4 v, ushort4& hi, ushort4& lo) {
  unsigned short h;
  h = f2bf(v.x); hi.x = h; lo.x = f2bf(v.x - bf2f(h));
  h = f2bf(v.y); hi.y = h; lo.y = f2bf(v.y - bf2f(h));
  h = f2bf(v.z); hi.z = h; lo.z = f2bf(v.z - bf2f(h));
  h = f2bf(v.w); hi.w = h; lo.w = f2bf(v.w - bf2f(h));
}

// ---------------- gamma/beta for both AdaLNs ----------------
__global__ __launch_bounds__(256) void gamma_beta_kernel(
    const float* __restrict__ pc,
    const float* __restrict__ g1w, const float* __restrict__ g1b,
    const float* __restrict__ b1w, const float* __restrict__ b1b,
    const float* __restrict__ g2w, const float* __restrict__ g2b,
    const float* __restrict__ b2w, const float* __restrict__ b2b,
    float* __restrict__ gamma1, float* __restrict__ beta1,
    float* __restrict__ gamma2, float* __restrict__ beta2) {
  int i = blockIdx.x * 256 + threadIdx.x;
  if (i >= B_ * D_) return;
  int b = i >> 8, d = i & 255;
  const float* p = pc + b * PDIM_;
  float s1 = 0.f, s2 = 0.f, s3 = 0.f, s4 = 0.f;
#pragma unroll 8
  for (int k = 0; k < PDIM_; ++k) {
    float pv = p[k];
    s1 += pv * g1w[d * PDIM_ + k];
    s2 += pv * b1w[d * PDIM_ + k];
    s3 += pv * g2w[d * PDIM_ + k];
    s4 += pv * b2w[d * PDIM_ + k];
  }
  gamma1[i] = s1 + g1b[d];
  beta1[i]  = s2 + b1b[d];
  gamma2[i] = s3 + g2b[d];
  beta2[i]  = s4 + b2b[d];
}

// ---------------- AdaLN (plain LN -> gamma*xhat+beta -> LN(w,b)) ----------------
__global__ __launch_bounds__(256) void adaln_kernel(
    const float* __restrict__ x, const float* __restrict__ gamma,
    const float* __restrict__ beta, const float* __restrict__ lnw,
    const float* __restrict__ lnb, float* __restrict__ out) {
  int wid = threadIdx.x >> 6, lane = threadIdx.x & 63;
  int r = blockIdx.x * 4 + wid;
  int b = r >> 10;
  const int c = lane << 2;
  float4 v = *(const float4*)&x[(size_t)r * D_ + c];
  float sum = wave_sum(v.x + v.y + v.z + v.w);
  float mu = sum * (1.f / D_);
  float d0 = v.x - mu, d1 = v.y - mu, d2 = v.z - mu, d3 = v.w - mu;
  float sq = wave_sum(d0 * d0 + d1 * d1 + d2 * d2 + d3 * d3);
  float rs = rsqrtf(sq * (1.f / D_) + EPS_);
  float4 g  = *(const float4*)&gamma[b * D_ + c];
  float4 be = *(const float4*)&beta[b * D_ + c];
  float a0 = g.x * (d0 * rs) + be.x;
  float a1 = g.y * (d1 * rs) + be.y;
  float a2 = g.z * (d2 * rs) + be.z;
  float a3 = g.w * (d3 * rs) + be.w;
  float sum2 = wave_sum(a0 + a1 + a2 + a3);
  float mu2 = sum2 * (1.f / D_);
  float e0 = a0 - mu2, e1 = a1 - mu2, e2 = a2 - mu2, e3 = a3 - mu2;
  float sq2 = wave_sum(e0 * e0 + e1 * e1 + e2 * e2 + e3 * e3);
  float rs2 = rsqrtf(sq2 * (1.f / D_) + EPS_);
  float4 w  = *(const float4*)&lnw[c];
  float4 bb = *(const float4*)&lnb[c];
  float4 o;
  o.x = e0 * rs2 * w.x + bb.x;
  o.y = e1 * rs2 * w.y + bb.y;
  o.z = e2 * rs2 * w.z + bb.z;
  o.w = e3 * rs2 * w.w + bb.w;
  *(float4*)&out[(size_t)r * D_ + c] = o;
}

// ---------------- split-bf16 MFMA GEMM: C[M,Nc] = A[M,K]@W[Nc,K]^T ----------------
// EPI: 0 none, 1 exact GELU, 2 +R, 3 split-QKV writeout (C is ushort* base).
// MS: 4 -> BM=128 tile, 2 -> BM=64 tile. BN=128. 4 waves in 2x2.
template <int EPI, int MS>
__global__ __launch_bounds__(256) void gemm_mfma_kernel(
    const float* __restrict__ A, const float* __restrict__ Wt,
    const float* __restrict__ bias, const float* __restrict__ R,
    float* __restrict__ C, int M, int Nc, int K) {
  __shared__ __align__(16) unsigned short Ah[MS * 32][40];
  __shared__ __align__(16) unsigned short Al[MS * 32][40];
  __shared__ __align__(16) unsigned short Bh[128][40];
  __shared__ __align__(16) unsigned short Bl[128][40];
  const int t = threadIdx.x;
  const int w = t >> 6, l = t & 63;
  const int lr = l & 15, lg = l >> 4;
  const int bm = blockIdx.y * (MS * 32), bn = blockIdx.x * 128;
  constexpr int SA = (MS == 4) ? 1 : 2;
  constexpr int NA = (MS == 4) ? 4 : 2;
  const int sra = t >> SA;
  const int ska = (t & ((1 << SA) - 1)) * (NA * 4);
  const int srb = t >> 1;
  const int skb = (t & 1) * 16;
  const float* Ap = A + (size_t)(bm + sra) * K + ska;
  const float* Bp = Wt + (size_t)(bn + srb) * K + skb;

  f32x4 acc[MS][4];
#pragma unroll
  for (int i = 0; i < MS; ++i)
#pragma unroll
    for (int j = 0; j < 4; ++j) acc[i][j] = (f32x4){0.f, 0.f, 0.f, 0.f};

  float4 ra[NA], rb[4];
#pragma unroll
  for (int c = 0; c < NA; ++c) ra[c] = *(const float4*)(Ap + c * 4);
#pragma unroll
  for (int c = 0; c < 4; ++c) rb[c] = *(const float4*)(Bp + c * 4);

  const int nk = K >> 5;
  for (int kt = 0; kt < nk; ++kt) {
    __syncthreads();
#pragma unroll
    for (int c = 0; c < NA; ++c) {
      ushort4 h4, l4;
      split4(ra[c], h4, l4);
      *(ushort4*)&Ah[sra][ska + c * 4] = h4;
      *(ushort4*)&Al[sra][ska + c * 4] = l4;
    }
#pragma unroll
    for (int c = 0; c < 4; ++c) {
      ushort4 h4, l4;
      split4(rb[c], h4, l4);
      *(ushort4*)&Bh[srb][skb + c * 4] = h4;
      *(ushort4*)&Bl[srb][skb + c * 4] = l4;
    }
    if (kt + 1 < nk) {
      Ap += 32;
      Bp += 32;
#pragma unroll
      for (int c = 0; c < NA; ++c) ra[c] = *(const float4*)(Ap + c * 4);
#pragma unroll
      for (int c = 0; c < 4; ++c) rb[c] = *(const float4*)(Bp + c * 4);
    }
    __syncthreads();
    bf16x8 bhj[4], blj[4];
#pragma unroll
    for (int j = 0; j < 4; ++j) {
      bhj[j] = *(const bf16x8*)&Bh[(w & 1) * 64 + j * 16 + lr][lg * 8];
      blj[j] = *(const bf16x8*)&Bl[(w & 1) * 64 + j * 16 + lr][lg * 8];
    }
#pragma unroll
    for (int i = 0; i < MS; ++i) {
      bf16x8 ahi = *(const bf16x8*)&Ah[(w >> 1) * (MS * 16) + i * 16 + lr][lg * 8];
      bf16x8 ali = *(const bf16x8*)&Al[(w >> 1) * (MS * 16) + i * 16 + lr][lg * 8];
#pragma unroll
      for (int j = 0; j < 4; ++j) {
        acc[i][j] = __builtin_amdgcn_mfma_f32_16x16x32_bf16(ahi, bhj[j], acc[i][j], 0, 0, 0);
        acc[i][j] = __builtin_amdgcn_mfma_f32_16x16x32_bf16(ali, bhj[j], acc[i][j], 0, 0, 0);
        acc[i][j] = __builtin_amdgcn_mfma_f32_16x16x32_bf16(ahi, blj[j], acc[i][j], 0, 0, 0);
      }
    }
  }
  // epilogue: m = bm + (w>>1)*MS*16 + i*16 + lg*4 + r ; n = bn + (w&1)*64 + j*16 + lr
#pragma unroll
  for (int i = 0; i < MS; ++i) {
    const int m0 = bm + (w >> 1) * (MS * 16) + i * 16 + lg * 4;
#pragma unroll
    for (int j = 0; j < 4; ++j) {
      const int n = bn + (w & 1) * 64 + j * 16 + lr;
      const float bv = bias ? bias[n] : 0.f;
#pragma unroll
      for (int r = 0; r < 4; ++r) {
        const int m = m0 + r;
        float v = acc[i][j][r] + bv;
        if constexpr (EPI == 3) {
          // split-QKV writeout: Q scaled by log2(e)/sqrt(32)
          const int sec = n >> 8, f = n & 255, hh = f >> 5, dd = f & 31;
          if (sec == 0) v *= 0.2550332772677823f;
          unsigned short hi = f2bf(v);
          unsigned short lo = f2bf(v - bf2f(hi));
          unsigned short* qs = (unsigned short*)C + (size_t)sec * QKV_SEC;
          const size_t base =
              ((size_t)((m >> 10) * H_ + hh) * S_ + (m & 1023)) * 32 + dd;
          qs[base] = hi;
          qs[base + QKV_LO] = lo;
        } else {
          const size_t idx = (size_t)m * Nc + n;
          if constexpr (EPI == 1) v = 0.5f * v * (1.f + erff(v * 0.7071067811865476f));
          if constexpr (EPI == 2) v += R[idx];
          C[idx] = v;
        }
      }
    }
  }
}

// ---------------- split-bf16 MFMA flash attention (pre-split inputs) ----------------
// Block = 4 waves; one (b,h); 128 q-rows/block (32/wave, 2 subtiles of 16).
// K/V already bf16 hi/lo in [B][H][S][32] — staging is pure copy, no math.
__global__ __launch_bounds__(256) void attn_kernel(
    const unsigned short* __restrict__ qkvs, float* __restrict__ ao) {
  __shared__ __align__(16) unsigned short KhL[64][40];
  __shared__ __align__(16) unsigned short KlL[64][40];
  __shared__ __align__(16) unsigned short VThL[32][72];
  __shared__ __align__(16) unsigned short VTlL[32][72];
  __shared__ __align__(16) unsigned short PhL[4][16][72];
  __shared__ __align__(16) unsigned short PlL[4][16][72];

  const int t = threadIdx.x;
  const int w = t >> 6;
  const int l = t & 63;
  const int lq = l & 15;
  const int g = l >> 4;
  const int qt = blockIdx.x, h = blockIdx.y, b = blockIdx.z;
  const int qbase = qt * 128 + w * 32;
  const size_t panel = (size_t)(b * H_ + h) * S_;  // row base in [B][H][S][32]

  const unsigned short* Qh_g = qkvs;
  const unsigned short* Ql_g = qkvs + QKV_LO;
  const unsigned short* Kh_g = qkvs + QKV_SEC;
  const unsigned short* Kl_g = qkvs + QKV_SEC + QKV_LO;
  const unsigned short* Vh_g = qkvs + 2 * QKV_SEC;
  const unsigned short* Vl_g = qkvs + 2 * QKV_SEC + QKV_LO;

  // Q fragments: direct 16B loads (pre-scaled, pre-split)
  bf16x8 qh[2], ql[2];
#pragma unroll
  for (int qs = 0; qs < 2; ++qs) {
    const size_t qi = (panel + qbase + qs * 16 + lq) * 32 + g * 8;
    qh[qs] = *(const bf16x8*)&Qh_g[qi];
    ql[qs] = *(const bf16x8*)&Ql_g[qi];
  }

  f32x4 oacc[2][2];
  float mrun[2], lrun[2];
#pragma unroll
  for (int qs = 0; qs < 2; ++qs) {
    oacc[qs][0] = (f32x4){0.f, 0.f, 0.f, 0.f};
    oacc[qs][1] = (f32x4){0.f, 0.f, 0.f, 0.f};
    mrun[qs] = -1e30f;
    lrun[qs] = 0.f;
  }

  const int key_s = t >> 2;  // 0..63
  const int dg = t & 3;      // dim group of 8

  for (int kt = 0; kt < 16; ++kt) {
    __syncthreads();
    // ---- stage K rows + V^T (pure copies) ----
    {
      const size_t kb = (panel + kt * 64 + key_s) * 32 + dg * 8;
      u16x8 khv = *(const u16x8*)&Kh_g[kb];
      u16x8 klv = *(const u16x8*)&Kl_g[kb];
      *(u16x8*)&KhL[key_s][dg * 8] = khv;
      *(u16x8*)&KlL[key_s][dg * 8] = klv;
      u16x8 vhv = *(const u16x8*)&Vh_g[kb];
      u16x8 vlv = *(const u16x8*)&Vl_g[kb];
#pragma unroll
      for (int j = 0; j < 8; ++j) {
        VThL[dg * 8 + j][key_s] = vhv[j];
        VTlL[dg * 8 + j][key_s] = vlv[j];
      }
    }
    __syncthreads();

    // hoisted K fragments (shared across the 2 q-subtiles)
    bf16x8 kfh[4], kfl[4];
#pragma unroll
    for (int i = 0; i < 4; ++i) {
      kfh[i] = *(const bf16x8*)&KhL[i * 16 + lq][g * 8];
      kfl[i] = *(const bf16x8*)&KlL[i * 16 + lq][g * 8];
    }

#pragma unroll
    for (int qs = 0; qs < 2; ++qs) {
      // ---- QK^T: S^T[key][q] ----
      f32x4 s[4];
#pragma unroll
      for (int i = 0; i < 4; ++i) {
        f32x4 c = (f32x4){0.f, 0.f, 0.f, 0.f};
        c = __builtin_amdgcn_mfma_f32_16x16x32_bf16(kfh[i], qh[qs], c, 0, 0, 0);
        c = __builtin_amdgcn_mfma_f32_16x16x32_bf16(kfh[i], ql[qs], c, 0, 0, 0);
        c = __builtin_amdgcn_mfma_f32_16x16x32_bf16(kfl[i], qh[qs], c, 0, 0, 0);
        s[i] = c;
      }
      // ---- online softmax (lane owns q=lq; keys 16i+4g+r) ----
      float pm = -1e30f;
#pragma unroll
      for (int i = 0; i < 4; ++i)
#pragma unroll
        for (int r = 0; r < 4; ++r) pm = fmaxf(pm, s[i][r]);
      pm = fmaxf(pm, __shfl_xor(pm, 16, 64));
      pm = fmaxf(pm, __shfl_xor(pm, 32, 64));
      float mnew = fmaxf(mrun[qs], pm);
      float rfac = exp2f(mrun[qs] - mnew);
      mrun[qs] = mnew;
      oacc[qs][0] *= rfac;
      oacc[qs][1] *= rfac;
      float lsum = 0.f;
#pragma unroll
      for (int i = 0; i < 4; ++i) {
        ushort4 hv, lv;
        unsigned short hr[4], lr4[4];
#pragma unroll
        for (int r = 0; r < 4; ++r) {
          float p = exp2f(s[i][r] - mnew);
          lsum += p;
          unsigned short ph = f2bf(p);
          hr[r] = ph;
          lr4[r] = f2bf(p - bf2f(ph));
        }
        hv.x = hr[0]; hv.y = hr[1]; hv.z = hr[2]; hv.w = hr[3];
        lv.x = lr4[0]; lv.y = lr4[1]; lv.z = lr4[2]; lv.w = lr4[3];
        *(ushort4*)&PhL[w][lq][i * 16 + g * 4] = hv;
        *(ushort4*)&PlL[w][lq][i * 16 + g * 4] = lv;
      }
      lsum += __shfl_xor(lsum, 16, 64);
      lsum += __shfl_xor(lsum, 32, 64);
      lrun[qs] = lrun[qs] * rfac + lsum;

      // ---- PV: O^T[dim][q] += V^T @ P^T ----
#pragma unroll
      for (int kh2 = 0; kh2 < 2; ++kh2) {
        bf16x8 pb = *(const bf16x8*)&PhL[w][lq][kh2 * 32 + g * 8];
        bf16x8 pl = *(const bf16x8*)&PlL[w][lq][kh2 * 32 + g * 8];
#pragma unroll
        for (int d = 0; d < 2; ++d) {
          bf16x8 vh = *(const bf16x8*)&VThL[d * 16 + lq][kh2 * 32 + g * 8];
          bf16x8 vl = *(const bf16x8*)&VTlL[d * 16 + lq][kh2 * 32 + g * 8];
          oacc[qs][d] = __builtin_amdgcn_mfma_f32_16x16x32_bf16(vh, pb, oacc[qs][d], 0, 0, 0);
          oacc[qs][d] = __builtin_amdgcn_mfma_f32_16x16x32_bf16(vh, pl, oacc[qs][d], 0, 0, 0);
          oacc[qs][d] = __builtin_amdgcn_mfma_f32_16x16x32_bf16(vl, pb, oacc[qs][d], 0, 0, 0);
        }
      }
    }
  }

  // ---- epilogue: lane holds O^T[dims d*16+4g+r][q=lq] ----
#pragma unroll
  for (int qs = 0; qs < 2; ++qs) {
    float inv = 1.f / lrun[qs];
    const size_t orow =
        ((size_t)(b * S_ + qbase + qs * 16 + lq)) * D_ + h * DH_;
#pragma unroll
    for (int d = 0; d < 2; ++d) {
      float4 ov;
      ov.x = oacc[qs][d][0] * inv;
      ov.y = oacc[qs][d][1] * inv;
      ov.z = oacc[qs][d][2] * inv;
      ov.w = oacc[qs][d][3] * inv;
      *(float4*)&ao[orow + d * 16 + g * 4] = ov;
    }
  }
}

// ---------------- a_src/a_dst: per-node dots ----------------
__global__ __launch_bounds__(256) void adot_kernel(
    const float* __restrict__ h, const float* __restrict__ att_src,
    const float* __restrict__ att_dst, float* __restrict__ a_src,
    float* __restrict__ a_dst) {
  int wid = threadIdx.x >> 6, lane = threadIdx.x & 63;
  int n = blockIdx.x * 4 + wid;
  const int c = lane << 2;
  float4 hv = *(const float4*)&h[(size_t)n * D_ + c];
  float4 as = *(const float4*)&att_src[c];
  float4 ad = *(const float4*)&att_dst[c];
  float s = hv.x * as.x + hv.y * as.y + hv.z * as.z + hv.w * as.w;
  float d = hv.x * ad.x + hv.y * ad.y + hv.z * ad.z + hv.w * ad.w;
  s = wave_sum(s);
  d = wave_sum(d);
  if (lane == 0) { a_src[n] = s; a_dst[n] = d; }
}

// ---------------- GAT CSR build ----------------
__global__ __launch_bounds__(256) void hist_kernel(
    const int* __restrict__ e_dst, int* __restrict__ counts) {
  int i = blockIdx.x * 256 + threadIdx.x;
  if (i >= ETOT_) return;
  int dst = (i < E_) ? e_dst[i] : (i - E_);
  atomicAdd(&counts[dst], 1);
}

__global__ __launch_bounds__(1024) void scan_kernel(
    const int* __restrict__ counts, int* __restrict__ offsets,
    int* __restrict__ cursor) {
  __shared__ int sums[1024];
  const int t = threadIdx.x;
  int local[16];
  int s = 0;
#pragma unroll
  for (int i = 0; i < 16; ++i) { local[i] = s; s += counts[t * 16 + i]; }
  sums[t] = s;
  __syncthreads();
  for (int off = 1; off < 1024; off <<= 1) {
    int v = (t >= off) ? sums[t - off] : 0;
    __syncthreads();
    sums[t] += v;
    __syncthreads();
  }
  int base = (t > 0) ? sums[t - 1] : 0;
#pragma unroll
  for (int i = 0; i < 16; ++i) {
    int o = base + local[i];
    offsets[t * 16 + i] = o;
    cursor[t * 16 + i] = o;
  }
  if (t == 1023) offsets[N_] = sums[1023];
}

__global__ __launch_bounds__(256) void scatter_kernel(
    const int* __restrict__ e_src, const int* __restrict__ e_dst,
    int* __restrict__ cursor, int* __restrict__ csr_src) {
  int i = blockIdx.x * 256 + threadIdx.x;
  if (i >= ETOT_) return;
  int s = (i < E_) ? e_src[i] : (i - E_);
  int d = (i < E_) ? e_dst[i] : (i - E_);
  int slot = atomicAdd(&cursor[d], 1);
  csr_src[slot] = s;
}

// ---------------- GAT aggregate + bias + residual + gLN (one wave per node) ----------------
__global__ __launch_bounds__(256) void gat_ln_kernel(
    const float* __restrict__ h, const float* __restrict__ a_src,
    const float* __restrict__ a_dst, const int* __restrict__ offsets,
    const int* __restrict__ csr_src, const float* __restrict__ gat_bias,
    const float* __restrict__ x1, const float* __restrict__ gln_w,
    const float* __restrict__ gln_b, float* __restrict__ x2) {
  int wid = threadIdx.x >> 6, lane = threadIdx.x & 63;
  int n = blockIdx.x * 4 + wid;
  const int c = lane << 2;
  int beg = offsets[n], end = offsets[n + 1];
  float adn = a_dst[n];
  float m = -1e30f;
  for (int j = beg + lane; j < end; j += 64) {
    float e = a_src[csr_src[j]] + adn;
    e = (e >= 0.f) ? e : 0.2f * e;
    m = fmaxf(m, e);
  }
  m = wave_max(m);
  float z = 0.f;
  float ac0 = 0.f, ac1 = 0.f, ac2 = 0.f, ac3 = 0.f;
  for (int j0 = beg; j0 < end; j0 += 64) {
    int j = j0 + lane;
    float wgt = 0.f;
    int sidx = 0;
    if (j < end) {
      sidx = csr_src[j];
      float e = a_src[sidx] + adn;
      e = (e >= 0.f) ? e : 0.2f * e;
      wgt = __expf(e - m);
    }
    z += wgt;
    int cnt = min(64, end - j0);
    for (int jj = 0; jj < cnt; ++jj) {
      float ww = __shfl(wgt, jj, 64);
      int ss = __shfl(sidx, jj, 64);
      float4 hv = *(const float4*)&h[(size_t)ss * D_ + c];
      ac0 += ww * hv.x; ac1 += ww * hv.y; ac2 += ww * hv.z; ac3 += ww * hv.w;
    }
  }
  z = wave_sum(z);
  float inv = 1.f / z;
  float4 bv = *(const float4*)&gat_bias[c];
  float4 xv = *(const float4*)&x1[(size_t)n * D_ + c];
  float v0 = ac0 * inv + bv.x + xv.x;
  float v1 = ac1 * inv + bv.y + xv.y;
  float v2 = ac2 * inv + bv.z + xv.z;
  float v3 = ac3 * inv + bv.w + xv.w;
  float sum = wave_sum(v0 + v1 + v2 + v3);
  float mu = sum * (1.f / D_);
  float d0 = v0 - mu, d1 = v1 - mu, d2 = v2 - mu, d3 = v3 - mu;
  float sq = wave_sum(d0 * d0 + d1 * d1 + d2 * d2 + d3 * d3);
  float rs = rsqrtf(sq * (1.f / D_) + EPS_);
  float4 w4 = *(const float4*)&gln_w[c];
  float4 b4 = *(const float4*)&gln_b[c];
  float4 o;
  o.x = d0 * rs * w4.x + b4.x;
  o.y = d1 * rs * w4.y + b4.y;
  o.z = d2 * rs * w4.z + b4.z;
  o.w = d3 * rs * w4.w + b4.w;
  *(float4*)&x2[(size_t)n * D_ + c] = o;
}

// ---------------- launch ----------------
extern "C" void kernel_launch(void* const* d_in, const int* in_sizes, int n_in,
                              void* d_out, int out_size, void* d_ws,
                              size_t ws_size, hipStream_t stream) {
  const float* x         = (const float*)d_in[0];
  const float* prop_cond = (const float*)d_in[1];
  const int*   edges     = (const int*)d_in[2];
  const float* a1gw = (const float*)d_in[3];
  const float* a1gb = (const float*)d_in[4];
  const float* a1bw = (const float*)d_in[5];
  const float* a1bb = (const float*)d_in[6];
  const float* a2gw = (const float*)d_in[7];
  const float* a2gb = (const float*)d_in[8];
  const float* a2bw = (const float*)d_in[9];
  const float* a2bb = (const float*)d_in[10];
  const float* ln1w = (const float*)d_in[11];
  const float* ln1b = (const float*)d_in[12];
  const float* ln2w = (const float*)d_in[13];
  const float* ln2b = (const float*)d_in[14];
  const float* glnw = (const float*)d_in[15];
  const float* glnb = (const float*)d_in[16];
  const float* ipw  = (const float*)d_in[17];
  const float* ipb  = (const float*)d_in[18];
  const float* opw  = (const float*)d_in[19];
  const float* opb  = (const float*)d_in[20];
  const float* f1w  = (const float*)d_in[21];
  const float* f1b  = (const float*)d_in[22];
  const float* f2w  = (const float*)d_in[23];
  const float* f2b  = (const float*)d_in[24];
  const float* gatw = (const float*)d_in[25];
  const float* gats = (const float*)d_in[26];
  const float* gatd = (const float*)d_in[27];
  const float* gatb = (const float*)d_in[28];
  float* out = (float*)d_out;

  const int* e_src = edges;
  const int* e_dst = edges + E_;

  float* W = (float*)d_ws;
  const size_t F_BIG = 0;
  const size_t F_XN  = F_BIG + 16777216;
  const size_t F_X1  = F_XN + 4194304;
  const size_t F_H   = F_X1 + 4194304;
  const size_t F_X2  = F_H + 4194304;
  const size_t F_GB  = F_X2 + 4194304;
  const size_t F_AS  = F_GB + 16384;
  const size_t F_AD  = F_AS + N_;
  const size_t F_INT = F_AD + N_;
  float* buf_big = W + F_BIG;
  float* buf_xn  = W + F_XN;
  float* buf_x1  = W + F_X1;
  float* buf_h   = W + F_H;
  float* buf_x2  = W + F_X2;
  float* gamma1  = W + F_GB;
  float* beta1   = gamma1 + 4096;
  float* gamma2  = beta1 + 4096;
  float* beta2   = gamma2 + 4096;
  float* a_src   = W + F_AS;
  float* a_dst   = W + F_AD;
  int* counts  = (int*)(W + F_INT);
  int* offsets = counts + N_;
  int* cursor  = offsets + N_ + 1;
  int* csr_src = cursor + N_;

  hipMemsetAsync(counts, 0, N_ * sizeof(int), stream);

  gamma_beta_kernel<<<16, 256, 0, stream>>>(prop_cond, a1gw, a1gb, a1bw, a1bb,
                                            a2gw, a2gb, a2bw, a2bb, gamma1,
                                            beta1, gamma2, beta2);
  adaln_kernel<<<N_ / 4, 256, 0, stream>>>(x, gamma1, beta1, ln1w, ln1b, buf_xn);
  // QKV projection + fused split/scale/transpose writeout
  gemm_mfma_kernel<3, 4><<<dim3(6, 128), 256, 0, stream>>>(
      buf_xn, ipw, ipb, nullptr, buf_big, N_, 768, 256);
  attn_kernel<<<dim3(8, 8, 16), 256, 0, stream>>>(
      (const unsigned short*)buf_big, buf_xn);
  // out_proj + residual(x)
  gemm_mfma_kernel<2, 2><<<dim3(2, 256), 256, 0, stream>>>(
      buf_xn, opw, opb, x, buf_x1, N_, 256, 256);
  // GAT h = x1 @ gat_w^T
  gemm_mfma_kernel<0, 2><<<dim3(2, 256), 256, 0, stream>>>(
      buf_x1, gatw, nullptr, nullptr, buf_h, N_, 256, 256);
  adot_kernel<<<N_ / 4, 256, 0, stream>>>(buf_h, gats, gatd, a_src, a_dst);
  hist_kernel<<<(ETOT_ + 255) / 256, 256, 0, stream>>>(e_dst, counts);
  scan_kernel<<<1, 1024, 0, stream>>>(counts, offsets, cursor);
  scatter_kernel<<<(ETOT_ + 255) / 256, 256, 0, stream>>>(e_src, e_dst, cursor,
                                                          csr_src);
  gat_ln_kernel<<<N_ / 4, 256, 0, stream>>>(buf_h, a_src, a_dst, offsets,
                                            csr_src, gatb, buf_x1, glnw, glnb,
                                            buf_x2);
  adaln_kernel<<<N_ / 4, 256, 0, stream>>>(buf_x2, gamma2, beta2, ln2w, ln2b,
                                           buf_xn);
  // FFN1 + GELU
  gemm_mfma_kernel<1, 4><<<dim3(8, 128), 256, 0, stream>>>(
      buf_xn, f1w, f1b, nullptr, buf_big, N_, DFF_, 256);
  // FFN2 + residual(x2)
  gemm_mfma_kernel<2, 2><<<dim3(2, 256), 256, 0, stream>>>(
      buf_big, f2w, f2b, buf_x2, out, N_, 256, DFF_);
}

// Round 9
// 476.762 us; speedup vs baseline: 2.2987x; 1.0318x over previous
//
#include <hip/hip_runtime.h>
#include <cmath>

#define B_    16
#define S_    1024
#define D_    256
#define H_    8
#define DH_   32
#define DFF_  1024
#define PDIM_ 64
#define N_    (B_ * S_)      // 16384
#define E_    262144
#define ETOT_ (E_ + N_)      // 278528
#define EPS_  1e-5f

typedef __attribute__((ext_vector_type(8))) short bf16x8;
typedef __attribute__((ext_vector_type(8))) unsigned short u16x8;
typedef __attribute__((ext_vector_type(4))) float f32x4;

// split-qkv buffer layout (ushort units), each array 4194304 elements:
// Qh at 0, Ql at 4194304, Kh at 8388608, Kl at 12582912, Vh at 16777216, Vl at 20971520
#define QKV_SEC 8388608
#define QKV_LO  4194304
// split-h layout for GAT: Hh at 0, Hl at 4194304 (ushort units)
#define H_LO    4194304

// ---------------- wave helpers ----------------
__device__ __forceinline__ float wave_sum(float v) {
#pragma unroll
  for (int m = 1; m < 64; m <<= 1) v += __shfl_xor(v, m, 64);
  return v;
}
__device__ __forceinline__ float wave_max(float v) {
#pragma unroll
  for (int m = 1; m < 64; m <<= 1) v = fmaxf(v, __shfl_xor(v, m, 64));
  return v;
}

// bf16 split helpers (RNE)
__device__ __forceinline__ unsigned short f2bf(float f) {
  unsigned int u = __float_as_uint(f);
  unsigned int r = u + 0x7fffu + ((u >> 16) & 1u);
  return (unsigned short)(r >> 16);
}
__device__ __forceinline__ float bf2f(unsigned short s) {
  return __uint_as_float(((unsigned int)s) << 16);
}
__device__ __forceinline__ void split4(float4 v, ushort4& hi, ushort4& lo) {
  unsigned short h;
  h = f2bf(v.x); hi.x = h; lo.x = f2bf(v.x - bf2f(h));
  h = f2bf(v.y); hi.y = h; lo.y = f2bf(v.y - bf2f(h));
  h = f2bf(v.z); hi.z = h; lo.z = f2bf(v.z - bf2f(h));
  h = f2bf(v.w); hi.w = h; lo.w = f2bf(v.w - bf2f(h));
}
__device__ __forceinline__ ushort4 hi4(float4 v) {
  ushort4 h;
  h.x = f2bf(v.x); h.y = f2bf(v.y); h.z = f2bf(v.z); h.w = f2bf(v.w);
  return h;
}

// ---------------- gamma/beta for both AdaLNs ----------------
__global__ __launch_bounds__(256) void gamma_beta_kernel(
    const float* __restrict__ pc,
    const float* __restrict__ g1w, const float* __restrict__ g1b,
    const float* __restrict__ b1w, const float* __restrict__ b1b,
    const float* __restrict__ g2w, const float* __restrict__ g2b,
    const float* __restrict__ b2w, const float* __restrict__ b2b,
    float* __restrict__ gamma1, float* __restrict__ beta1,
    float* __restrict__ gamma2, float* __restrict__ beta2) {
  int i = blockIdx.x * 256 + threadIdx.x;
  if (i >= B_ * D_) return;
  int b = i >> 8, d = i & 255;
  const float* p = pc + b * PDIM_;
  float s1 = 0.f, s2 = 0.f, s3 = 0.f, s4 = 0.f;
#pragma unroll 8
  for (int k = 0; k < PDIM_; ++k) {
    float pv = p[k];
    s1 += pv * g1w[d * PDIM_ + k];
    s2 += pv * b1w[d * PDIM_ + k];
    s3 += pv * g2w[d * PDIM_ + k];
    s4 += pv * b2w[d * PDIM_ + k];
  }
  gamma1[i] = s1 + g1b[d];
  beta1[i]  = s2 + b1b[d];
  gamma2[i] = s3 + g2b[d];
  beta2[i]  = s4 + b2b[d];
}

// ---------------- AdaLN (plain LN -> gamma*xhat+beta -> LN(w,b)) ----------------
__global__ __launch_bounds__(256) void adaln_kernel(
    const float* __restrict__ x, const float* __restrict__ gamma,
    const float* __restrict__ beta, const float* __restrict__ lnw,
    const float* __restrict__ lnb, float* __restrict__ out) {
  int wid = threadIdx.x >> 6, lane = threadIdx.x & 63;
  int r = blockIdx.x * 4 + wid;
  int b = r >> 10;
  const int c = lane << 2;
  float4 v = *(const float4*)&x[(size_t)r * D_ + c];
  float sum = wave_sum(v.x + v.y + v.z + v.w);
  float mu = sum * (1.f / D_);
  float d0 = v.x - mu, d1 = v.y - mu, d2 = v.z - mu, d3 = v.w - mu;
  float sq = wave_sum(d0 * d0 + d1 * d1 + d2 * d2 + d3 * d3);
  float rs = rsqrtf(sq * (1.f / D_) + EPS_);
  float4 g  = *(const float4*)&gamma[b * D_ + c];
  float4 be = *(const float4*)&beta[b * D_ + c];
  float a0 = g.x * (d0 * rs) + be.x;
  float a1 = g.y * (d1 * rs) + be.y;
  float a2 = g.z * (d2 * rs) + be.z;
  float a3 = g.w * (d3 * rs) + be.w;
  float sum2 = wave_sum(a0 + a1 + a2 + a3);
  float mu2 = sum2 * (1.f / D_);
  float e0 = a0 - mu2, e1 = a1 - mu2, e2 = a2 - mu2, e3 = a3 - mu2;
  float sq2 = wave_sum(e0 * e0 + e1 * e1 + e2 * e2 + e3 * e3);
  float rs2 = rsqrtf(sq2 * (1.f / D_) + EPS_);
  float4 w  = *(const float4*)&lnw[c];
  float4 bb = *(const float4*)&lnb[c];
  float4 o;
  o.x = e0 * rs2 * w.x + bb.x;
  o.y = e1 * rs2 * w.y + bb.y;
  o.z = e2 * rs2 * w.z + bb.z;
  o.w = e3 * rs2 * w.w + bb.w;
  *(float4*)&out[(size_t)r * D_ + c] = o;
}

// ---------------- split-bf16 MFMA GEMM: C[M,Nc] = A[M,K]@W[Nc,K]^T ----------------
// A split hi+lo (2 MFMAs: a_full x b_hi); B hi only (weights are 0.02-scale,
// dropped a_hi x b_lo term ~2^-9 relative — below the pipeline's error floor).
// EPI: 0 none, 1 exact GELU, 2 +R, 3 split-QKV writeout, 4 split-h writeout.
// MS: 4 -> BM=128 tile, 2 -> BM=64 tile. BN=128. 4 waves in 2x2.
template <int EPI, int MS>
__global__ __launch_bounds__(256) void gemm_mfma_kernel(
    const float* __restrict__ A, const float* __restrict__ Wt,
    const float* __restrict__ bias, const float* __restrict__ R,
    float* __restrict__ C, int M, int Nc, int K) {
  __shared__ __align__(16) unsigned short Ah[MS * 32][40];
  __shared__ __align__(16) unsigned short Al[MS * 32][40];
  __shared__ __align__(16) unsigned short Bh[128][40];
  const int t = threadIdx.x;
  const int w = t >> 6, l = t & 63;
  const int lr = l & 15, lg = l >> 4;
  const int bm = blockIdx.y * (MS * 32), bn = blockIdx.x * 128;
  constexpr int SA = (MS == 4) ? 1 : 2;
  constexpr int NA = (MS == 4) ? 4 : 2;
  const int sra = t >> SA;
  const int ska = (t & ((1 << SA) - 1)) * (NA * 4);
  const int srb = t >> 1;
  const int skb = (t & 1) * 16;
  const float* Ap = A + (size_t)(bm + sra) * K + ska;
  const float* Bp = Wt + (size_t)(bn + srb) * K + skb;

  f32x4 acc[MS][4];
#pragma unroll
  for (int i = 0; i < MS; ++i)
#pragma unroll
    for (int j = 0; j < 4; ++j) acc[i][j] = (f32x4){0.f, 0.f, 0.f, 0.f};

  float4 ra[NA], rb[4];
#pragma unroll
  for (int c = 0; c < NA; ++c) ra[c] = *(const float4*)(Ap + c * 4);
#pragma unroll
  for (int c = 0; c < 4; ++c) rb[c] = *(const float4*)(Bp + c * 4);

  const int nk = K >> 5;
  for (int kt = 0; kt < nk; ++kt) {
    __syncthreads();
#pragma unroll
    for (int c = 0; c < NA; ++c) {
      ushort4 h4, l4;
      split4(ra[c], h4, l4);
      *(ushort4*)&Ah[sra][ska + c * 4] = h4;
      *(ushort4*)&Al[sra][ska + c * 4] = l4;
    }
#pragma unroll
    for (int c = 0; c < 4; ++c) {
      *(ushort4*)&Bh[srb][skb + c * 4] = hi4(rb[c]);
    }
    if (kt + 1 < nk) {
      Ap += 32;
      Bp += 32;
#pragma unroll
      for (int c = 0; c < NA; ++c) ra[c] = *(const float4*)(Ap + c * 4);
#pragma unroll
      for (int c = 0; c < 4; ++c) rb[c] = *(const float4*)(Bp + c * 4);
    }
    __syncthreads();
    bf16x8 bhj[4];
#pragma unroll
    for (int j = 0; j < 4; ++j) {
      bhj[j] = *(const bf16x8*)&Bh[(w & 1) * 64 + j * 16 + lr][lg * 8];
    }
#pragma unroll
    for (int i = 0; i < MS; ++i) {
      bf16x8 ahi = *(const bf16x8*)&Ah[(w >> 1) * (MS * 16) + i * 16 + lr][lg * 8];
      bf16x8 ali = *(const bf16x8*)&Al[(w >> 1) * (MS * 16) + i * 16 + lr][lg * 8];
#pragma unroll
      for (int j = 0; j < 4; ++j) {
        acc[i][j] = __builtin_amdgcn_mfma_f32_16x16x32_bf16(ahi, bhj[j], acc[i][j], 0, 0, 0);
        acc[i][j] = __builtin_amdgcn_mfma_f32_16x16x32_bf16(ali, bhj[j], acc[i][j], 0, 0, 0);
      }
    }
  }
  // epilogue: m = bm + (w>>1)*MS*16 + i*16 + lg*4 + r ; n = bn + (w&1)*64 + j*16 + lr
#pragma unroll
  for (int i = 0; i < MS; ++i) {
    const int m0 = bm + (w >> 1) * (MS * 16) + i * 16 + lg * 4;
#pragma unroll
    for (int j = 0; j < 4; ++j) {
      const int n = bn + (w & 1) * 64 + j * 16 + lr;
      const float bv = bias ? bias[n] : 0.f;
#pragma unroll
      for (int r = 0; r < 4; ++r) {
        const int m = m0 + r;
        float v = acc[i][j][r] + bv;
        if constexpr (EPI == 3) {
          // split-QKV writeout: Q scaled by log2(e)/sqrt(32)
          const int sec = n >> 8, f = n & 255, hh = f >> 5, dd = f & 31;
          if (sec == 0) v *= 0.2550332772677823f;
          unsigned short hi = f2bf(v);
          unsigned short lo = f2bf(v - bf2f(hi));
          unsigned short* qs = (unsigned short*)C + (size_t)sec * QKV_SEC;
          const size_t base =
              ((size_t)((m >> 10) * H_ + hh) * S_ + (m & 1023)) * 32 + dd;
          qs[base] = hi;
          qs[base + QKV_LO] = lo;
        } else if constexpr (EPI == 4) {
          // split-h writeout for GAT (hi for gather, hi+lo for adot)
          unsigned short hi = f2bf(v);
          unsigned short lo = f2bf(v - bf2f(hi));
          unsigned short* hs = (unsigned short*)C;
          const size_t base = (size_t)m * D_ + n;
          hs[base] = hi;
          hs[base + H_LO] = lo;
        } else {
          const size_t idx = (size_t)m * Nc + n;
          if constexpr (EPI == 1) v = 0.5f * v * (1.f + erff(v * 0.7071067811865476f));
          if constexpr (EPI == 2) v += R[idx];
          C[idx] = v;
        }
      }
    }
  }
}

// ---------------- split-bf16 MFMA flash attention (pre-split inputs) ----------------
// Block = 4 waves; one (b,h); 128 q-rows/block (32/wave, 2 subtiles of 16).
// K/V already bf16 hi/lo in [B][H][S][32] — staging is pure copy, no math.
__global__ __launch_bounds__(256) void attn_kernel(
    const unsigned short* __restrict__ qkvs, float* __restrict__ ao) {
  __shared__ __align__(16) unsigned short KhL[64][40];
  __shared__ __align__(16) unsigned short KlL[64][40];
  __shared__ __align__(16) unsigned short VThL[32][72];
  __shared__ __align__(16) unsigned short VTlL[32][72];
  __shared__ __align__(16) unsigned short PhL[4][16][72];
  __shared__ __align__(16) unsigned short PlL[4][16][72];

  const int t = threadIdx.x;
  const int w = t >> 6;
  const int l = t & 63;
  const int lq = l & 15;
  const int g = l >> 4;
  const int qt = blockIdx.x, h = blockIdx.y, b = blockIdx.z;
  const int qbase = qt * 128 + w * 32;
  const size_t panel = (size_t)(b * H_ + h) * S_;  // row base in [B][H][S][32]

  const unsigned short* Qh_g = qkvs;
  const unsigned short* Ql_g = qkvs + QKV_LO;
  const unsigned short* Kh_g = qkvs + QKV_SEC;
  const unsigned short* Kl_g = qkvs + QKV_SEC + QKV_LO;
  const unsigned short* Vh_g = qkvs + 2 * QKV_SEC;
  const unsigned short* Vl_g = qkvs + 2 * QKV_SEC + QKV_LO;

  // Q fragments: direct 16B loads (pre-scaled, pre-split)
  bf16x8 qh[2], ql[2];
#pragma unroll
  for (int qs = 0; qs < 2; ++qs) {
    const size_t qi = (panel + qbase + qs * 16 + lq) * 32 + g * 8;
    qh[qs] = *(const bf16x8*)&Qh_g[qi];
    ql[qs] = *(const bf16x8*)&Ql_g[qi];
  }

  f32x4 oacc[2][2];
  float mrun[2], lrun[2];
#pragma unroll
  for (int qs = 0; qs < 2; ++qs) {
    oacc[qs][0] = (f32x4){0.f, 0.f, 0.f, 0.f};
    oacc[qs][1] = (f32x4){0.f, 0.f, 0.f, 0.f};
    mrun[qs] = -1e30f;
    lrun[qs] = 0.f;
  }

  const int key_s = t >> 2;  // 0..63
  const int dg = t & 3;      // dim group of 8

  for (int kt = 0; kt < 16; ++kt) {
    __syncthreads();
    // ---- stage K rows + V^T (pure copies) ----
    {
      const size_t kb = (panel + kt * 64 + key_s) * 32 + dg * 8;
      u16x8 khv = *(const u16x8*)&Kh_g[kb];
      u16x8 klv = *(const u16x8*)&Kl_g[kb];
      *(u16x8*)&KhL[key_s][dg * 8] = khv;
      *(u16x8*)&KlL[key_s][dg * 8] = klv;
      u16x8 vhv = *(const u16x8*)&Vh_g[kb];
      u16x8 vlv = *(const u16x8*)&Vl_g[kb];
#pragma unroll
      for (int j = 0; j < 8; ++j) {
        VThL[dg * 8 + j][key_s] = vhv[j];
        VTlL[dg * 8 + j][key_s] = vlv[j];
      }
    }
    __syncthreads();

    // hoisted K fragments (shared across the 2 q-subtiles)
    bf16x8 kfh[4], kfl[4];
#pragma unroll
    for (int i = 0; i < 4; ++i) {
      kfh[i] = *(const bf16x8*)&KhL[i * 16 + lq][g * 8];
      kfl[i] = *(const bf16x8*)&KlL[i * 16 + lq][g * 8];
    }

#pragma unroll
    for (int qs = 0; qs < 2; ++qs) {
      // ---- QK^T: S^T[key][q] ----
      f32x4 s[4];
#pragma unroll
      for (int i = 0; i < 4; ++i) {
        f32x4 c = (f32x4){0.f, 0.f, 0.f, 0.f};
        c = __builtin_amdgcn_mfma_f32_16x16x32_bf16(kfh[i], qh[qs], c, 0, 0, 0);
        c = __builtin_amdgcn_mfma_f32_16x16x32_bf16(kfh[i], ql[qs], c, 0, 0, 0);
        c = __builtin_amdgcn_mfma_f32_16x16x32_bf16(kfl[i], qh[qs], c, 0, 0, 0);
        s[i] = c;
      }
      // ---- online softmax (lane owns q=lq; keys 16i+4g+r) ----
      float pm = -1e30f;
#pragma unroll
      for (int i = 0; i < 4; ++i)
#pragma unroll
        for (int r = 0; r < 4; ++r) pm = fmaxf(pm, s[i][r]);
      pm = fmaxf(pm, __shfl_xor(pm, 16, 64));
      pm = fmaxf(pm, __shfl_xor(pm, 32, 64));
      float mnew = fmaxf(mrun[qs], pm);
      float rfac = exp2f(mrun[qs] - mnew);
      mrun[qs] = mnew;
      oacc[qs][0] *= rfac;
      oacc[qs][1] *= rfac;
      float lsum = 0.f;
#pragma unroll
      for (int i = 0; i < 4; ++i) {
        ushort4 hv, lv;
        unsigned short hr[4], lr4[4];
#pragma unroll
        for (int r = 0; r < 4; ++r) {
          float p = exp2f(s[i][r] - mnew);
          lsum += p;
          unsigned short ph = f2bf(p);
          hr[r] = ph;
          lr4[r] = f2bf(p - bf2f(ph));
        }
        hv.x = hr[0]; hv.y = hr[1]; hv.z = hr[2]; hv.w = hr[3];
        lv.x = lr4[0]; lv.y = lr4[1]; lv.z = lr4[2]; lv.w = lr4[3];
        *(ushort4*)&PhL[w][lq][i * 16 + g * 4] = hv;
        *(ushort4*)&PlL[w][lq][i * 16 + g * 4] = lv;
      }
      lsum += __shfl_xor(lsum, 16, 64);
      lsum += __shfl_xor(lsum, 32, 64);
      lrun[qs] = lrun[qs] * rfac + lsum;

      // ---- PV: O^T[dim][q] += V^T @ P^T ----
#pragma unroll
      for (int kh2 = 0; kh2 < 2; ++kh2) {
        bf16x8 pb = *(const bf16x8*)&PhL[w][lq][kh2 * 32 + g * 8];
        bf16x8 pl = *(const bf16x8*)&PlL[w][lq][kh2 * 32 + g * 8];
#pragma unroll
        for (int d = 0; d < 2; ++d) {
          bf16x8 vh = *(const bf16x8*)&VThL[d * 16 + lq][kh2 * 32 + g * 8];
          bf16x8 vl = *(const bf16x8*)&VTlL[d * 16 + lq][kh2 * 32 + g * 8];
          oacc[qs][d] = __builtin_amdgcn_mfma_f32_16x16x32_bf16(vh, pb, oacc[qs][d], 0, 0, 0);
          oacc[qs][d] = __builtin_amdgcn_mfma_f32_16x16x32_bf16(vh, pl, oacc[qs][d], 0, 0, 0);
          oacc[qs][d] = __builtin_amdgcn_mfma_f32_16x16x32_bf16(vl, pb, oacc[qs][d], 0, 0, 0);
        }
      }
    }
  }

  // ---- epilogue: lane holds O^T[dims d*16+4g+r][q=lq] ----
#pragma unroll
  for (int qs = 0; qs < 2; ++qs) {
    float inv = 1.f / lrun[qs];
    const size_t orow =
        ((size_t)(b * S_ + qbase + qs * 16 + lq)) * D_ + h * DH_;
#pragma unroll
    for (int d = 0; d < 2; ++d) {
      float4 ov;
      ov.x = oacc[qs][d][0] * inv;
      ov.y = oacc[qs][d][1] * inv;
      ov.z = oacc[qs][d][2] * inv;
      ov.w = oacc[qs][d][3] * inv;
      *(float4*)&ao[orow + d * 16 + g * 4] = ov;
    }
  }
}

// ---------------- a_src/a_dst: per-node dots (split-bf16 h) ----------------
__global__ __launch_bounds__(256) void adot_kernel(
    const unsigned short* __restrict__ hs, const float* __restrict__ att_src,
    const float* __restrict__ att_dst, float* __restrict__ a_src,
    float* __restrict__ a_dst) {
  int wid = threadIdx.x >> 6, lane = threadIdx.x & 63;
  int n = blockIdx.x * 4 + wid;
  const int c = lane << 2;
  ushort4 hh = *(const ushort4*)&hs[(size_t)n * D_ + c];
  ushort4 hl = *(const ushort4*)&hs[H_LO + (size_t)n * D_ + c];
  float h0 = bf2f(hh.x) + bf2f(hl.x);
  float h1 = bf2f(hh.y) + bf2f(hl.y);
  float h2 = bf2f(hh.z) + bf2f(hl.z);
  float h3 = bf2f(hh.w) + bf2f(hl.w);
  float4 as = *(const float4*)&att_src[c];
  float4 ad = *(const float4*)&att_dst[c];
  float s = h0 * as.x + h1 * as.y + h2 * as.z + h3 * as.w;
  float d = h0 * ad.x + h1 * ad.y + h2 * ad.z + h3 * ad.w;
  s = wave_sum(s);
  d = wave_sum(d);
  if (lane == 0) { a_src[n] = s; a_dst[n] = d; }
}

// ---------------- GAT CSR build ----------------
__global__ __launch_bounds__(256) void hist_kernel(
    const int* __restrict__ e_dst, int* __restrict__ counts) {
  int i = blockIdx.x * 256 + threadIdx.x;
  if (i >= ETOT_) return;
  int dst = (i < E_) ? e_dst[i] : (i - E_);
  atomicAdd(&counts[dst], 1);
}

__global__ __launch_bounds__(1024) void scan_kernel(
    const int* __restrict__ counts, int* __restrict__ offsets,
    int* __restrict__ cursor) {
  __shared__ int sums[1024];
  const int t = threadIdx.x;
  int local[16];
  int s = 0;
#pragma unroll
  for (int i = 0; i < 16; ++i) { local[i] = s; s += counts[t * 16 + i]; }
  sums[t] = s;
  __syncthreads();
  for (int off = 1; off < 1024; off <<= 1) {
    int v = (t >= off) ? sums[t - off] : 0;
    __syncthreads();
    sums[t] += v;
    __syncthreads();
  }
  int base = (t > 0) ? sums[t - 1] : 0;
#pragma unroll
  for (int i = 0; i < 16; ++i) {
    int o = base + local[i];
    offsets[t * 16 + i] = o;
    cursor[t * 16 + i] = o;
  }
  if (t == 1023) offsets[N_] = sums[1023];
}

__global__ __launch_bounds__(256) void scatter_kernel(
    const int* __restrict__ e_src, const int* __restrict__ e_dst,
    int* __restrict__ cursor, int* __restrict__ csr_src) {
  int i = blockIdx.x * 256 + threadIdx.x;
  if (i >= ETOT_) return;
  int s = (i < E_) ? e_src[i] : (i - E_);
  int d = (i < E_) ? e_dst[i] : (i - E_);
  int slot = atomicAdd(&cursor[d], 1);
  csr_src[slot] = s;
}

// ---------------- GAT aggregate + bias + residual + gLN (one wave per node) ----------------
// gathers bf16-hi h (halved traffic vs fp32)
__global__ __launch_bounds__(256) void gat_ln_kernel(
    const unsigned short* __restrict__ hs, const float* __restrict__ a_src,
    const float* __restrict__ a_dst, const int* __restrict__ offsets,
    const int* __restrict__ csr_src, const float* __restrict__ gat_bias,
    const float* __restrict__ x1, const float* __restrict__ gln_w,
    const float* __restrict__ gln_b, float* __restrict__ x2) {
  int wid = threadIdx.x >> 6, lane = threadIdx.x & 63;
  int n = blockIdx.x * 4 + wid;
  const int c = lane << 2;
  int beg = offsets[n], end = offsets[n + 1];
  float adn = a_dst[n];
  float m = -1e30f;
  for (int j = beg + lane; j < end; j += 64) {
    float e = a_src[csr_src[j]] + adn;
    e = (e >= 0.f) ? e : 0.2f * e;
    m = fmaxf(m, e);
  }
  m = wave_max(m);
  float z = 0.f;
  float ac0 = 0.f, ac1 = 0.f, ac2 = 0.f, ac3 = 0.f;
  for (int j0 = beg; j0 < end; j0 += 64) {
    int j = j0 + lane;
    float wgt = 0.f;
    int sidx = 0;
    if (j < end) {
      sidx = csr_src[j];
      float e = a_src[sidx] + adn;
      e = (e >= 0.f) ? e : 0.2f * e;
      wgt = __expf(e - m);
    }
    z += wgt;
    int cnt = min(64, end - j0);
    for (int jj = 0; jj < cnt; ++jj) {
      float ww = __shfl(wgt, jj, 64);
      int ss = __shfl(sidx, jj, 64);
      ushort4 hv = *(const ushort4*)&hs[(size_t)ss * D_ + c];
      ac0 += ww * bf2f(hv.x);
      ac1 += ww * bf2f(hv.y);
      ac2 += ww * bf2f(hv.z);
      ac3 += ww * bf2f(hv.w);
    }
  }
  z = wave_sum(z);
  float inv = 1.f / z;
  float4 bv = *(const float4*)&gat_bias[c];
  float4 xv = *(const float4*)&x1[(size_t)n * D_ + c];
  float v0 = ac0 * inv + bv.x + xv.x;
  float v1 = ac1 * inv + bv.y + xv.y;
  float v2 = ac2 * inv + bv.z + xv.z;
  float v3 = ac3 * inv + bv.w + xv.w;
  float sum = wave_sum(v0 + v1 + v2 + v3);
  float mu = sum * (1.f / D_);
  float d0 = v0 - mu, d1 = v1 - mu, d2 = v2 - mu, d3 = v3 - mu;
  float sq = wave_sum(d0 * d0 + d1 * d1 + d2 * d2 + d3 * d3);
  float rs = rsqrtf(sq * (1.f / D_) + EPS_);
  float4 w4 = *(const float4*)&gln_w[c];
  float4 b4 = *(const float4*)&gln_b[c];
  float4 o;
  o.x = d0 * rs * w4.x + b4.x;
  o.y = d1 * rs * w4.y + b4.y;
  o.z = d2 * rs * w4.z + b4.z;
  o.w = d3 * rs * w4.w + b4.w;
  *(float4*)&x2[(size_t)n * D_ + c] = o;
}

// ---------------- launch ----------------
extern "C" void kernel_launch(void* const* d_in, const int* in_sizes, int n_in,
                              void* d_out, int out_size, void* d_ws,
                              size_t ws_size, hipStream_t stream) {
  const float* x         = (const float*)d_in[0];
  const float* prop_cond = (const float*)d_in[1];
  const int*   edges     = (const int*)d_in[2];
  const float* a1gw = (const float*)d_in[3];
  const float* a1gb = (const float*)d_in[4];
  const float* a1bw = (const float*)d_in[5];
  const float* a1bb = (const float*)d_in[6];
  const float* a2gw = (const float*)d_in[7];
  const float* a2gb = (const float*)d_in[8];
  const float* a2bw = (const float*)d_in[9];
  const float* a2bb = (const float*)d_in[10];
  const float* ln1w = (const float*)d_in[11];
  const float* ln1b = (const float*)d_in[12];
  const float* ln2w = (const float*)d_in[13];
  const float* ln2b = (const float*)d_in[14];
  const float* glnw = (const float*)d_in[15];
  const float* glnb = (const float*)d_in[16];
  const float* ipw  = (const float*)d_in[17];
  const float* ipb  = (const float*)d_in[18];
  const float* opw  = (const float*)d_in[19];
  const float* opb  = (const float*)d_in[20];
  const float* f1w  = (const float*)d_in[21];
  const float* f1b  = (const float*)d_in[22];
  const float* f2w  = (const float*)d_in[23];
  const float* f2b  = (const float*)d_in[24];
  const float* gatw = (const float*)d_in[25];
  const float* gats = (const float*)d_in[26];
  const float* gatd = (const float*)d_in[27];
  const float* gatb = (const float*)d_in[28];
  float* out = (float*)d_out;

  const int* e_src = edges;
  const int* e_dst = edges + E_;

  float* W = (float*)d_ws;
  const size_t F_BIG = 0;
  const size_t F_XN  = F_BIG + 16777216;
  const size_t F_X1  = F_XN + 4194304;
  const size_t F_H   = F_X1 + 4194304;
  const size_t F_X2  = F_H + 4194304;
  const size_t F_GB  = F_X2 + 4194304;
  const size_t F_AS  = F_GB + 16384;
  const size_t F_AD  = F_AS + N_;
  const size_t F_INT = F_AD + N_;
  float* buf_big = W + F_BIG;
  float* buf_xn  = W + F_XN;
  float* buf_x1  = W + F_X1;
  float* buf_h   = W + F_H;   // holds split-h (Hh, Hl) as ushort arrays
  float* buf_x2  = W + F_X2;
  float* gamma1  = W + F_GB;
  float* beta1   = gamma1 + 4096;
  float* gamma2  = beta1 + 4096;
  float* beta2   = gamma2 + 4096;
  float* a_src   = W + F_AS;
  float* a_dst   = W + F_AD;
  int* counts  = (int*)(W + F_INT);
  int* offsets = counts + N_;
  int* cursor  = offsets + N_ + 1;
  int* csr_src = cursor + N_;

  hipMemsetAsync(counts, 0, N_ * sizeof(int), stream);

  gamma_beta_kernel<<<16, 256, 0, stream>>>(prop_cond, a1gw, a1gb, a1bw, a1bb,
                                            a2gw, a2gb, a2bw, a2bb, gamma1,
                                            beta1, gamma2, beta2);
  adaln_kernel<<<N_ / 4, 256, 0, stream>>>(x, gamma1, beta1, ln1w, ln1b, buf_xn);
  // QKV projection + fused split/scale/transpose writeout
  gemm_mfma_kernel<3, 4><<<dim3(6, 128), 256, 0, stream>>>(
      buf_xn, ipw, ipb, nullptr, buf_big, N_, 768, 256);
  attn_kernel<<<dim3(8, 8, 16), 256, 0, stream>>>(
      (const unsigned short*)buf_big, buf_xn);
  // out_proj + residual(x)
  gemm_mfma_kernel<2, 2><<<dim3(2, 256), 256, 0, stream>>>(
      buf_xn, opw, opb, x, buf_x1, N_, 256, 256);
  // GAT h = x1 @ gat_w^T  -> split-bf16 writeout
  gemm_mfma_kernel<4, 2><<<dim3(2, 256), 256, 0, stream>>>(
      buf_x1, gatw, nullptr, nullptr, buf_h, N_, 256, 256);
  adot_kernel<<<N_ / 4, 256, 0, stream>>>((const unsigned short*)buf_h, gats,
                                          gatd, a_src, a_dst);
  hist_kernel<<<(ETOT_ + 255) / 256, 256, 0, stream>>>(e_dst, counts);
  scan_kernel<<<1, 1024, 0, stream>>>(counts, offsets, cursor);
  scatter_kernel<<<(ETOT_ + 255) / 256, 256, 0, stream>>>(e_src, e_dst, cursor,
                                                          csr_src);
  gat_ln_kernel<<<N_ / 4, 256, 0, stream>>>((const unsigned short*)buf_h,
                                            a_src, a_dst, offsets, csr_src,
                                            gatb, buf_x1, glnw, glnb, buf_x2);
  adaln_kernel<<<N_ / 4, 256, 0, stream>>>(buf_x2, gamma2, beta2, ln2w, ln2b,
                                           buf_xn);
  // FFN1 + GELU
  gemm_mfma_kernel<1, 4><<<dim3(8, 128), 256, 0, stream>>>(
      buf_xn, f1w, f1b, nullptr, buf_big, N_, DFF_, 256);
  // FFN2 + residual(x2)
  gemm_mfma_kernel<2, 2><<<dim3(2, 256), 256, 0, stream>>>(
      buf_big, f2w, f2b, buf_x2, out, N_, 256, DFF_);
}